// Round 11
// baseline (725.936 us; speedup 1.0000x reference)
//
#include <hip/hip_runtime.h>
#include <hip/hip_bf16.h>
#include <math.h>

// ---------------------------------------------------------------------------
// GCN link-prediction encoder: 6 GCN layers + dot-product decoder.
// R11 (on R9 base, 672us):
//  (1) k_premul: pairs.y = dinv[row]*ew  -> aggregates lose the dependent
//      dinv gather + 1 mul/edge; dest d factored out to the epilogue.
//  (2) aggregates software-pipeline the pairs-block prefetch (one gather
//      round-trip per 8-edge block instead of two).
//  (3) layer 1 aggregate-first: T=A_hat@x (64ch bf16), then GEMM 64->128
//      with fused bias+relu epilogue.
// ---------------------------------------------------------------------------

using bf16x8 = __attribute__((ext_vector_type(8))) short;  // 8 bf16 = 4 VGPRs
using f32x4  = __attribute__((ext_vector_type(4))) float;

__device__ inline unsigned f2bf_bits(float f) {            // RNE f32 -> bf16
    unsigned u = __float_as_uint(f);
    return (u + 0x7fffu + ((u >> 16) & 1u)) >> 16;
}
__device__ inline float bflo(unsigned w) { return __uint_as_float(w << 16); }
__device__ inline float bfhi(unsigned w) { return __uint_as_float(w & 0xffff0000u); }

// ---------------- CSR build (int-only atomics) ----------------

__global__ void k_zero(int* __restrict__ hist, int n) {
    int i = blockIdx.x * 256 + threadIdx.x;
    if (i < n) hist[i] = 0;
}

// histogram + per-edge slot reservation (fetch-add return)
__global__ void k_hist(const int* __restrict__ col, int* __restrict__ hist,
                       int* __restrict__ pos, int E) {
    int i = blockIdx.x * 256 + threadIdx.x;
    if (i < E) pos[i] = atomicAdd(&hist[col[i]], 1);
}

__global__ __launch_bounds__(256) void k_scan1(const int* __restrict__ hist,
                                               int* __restrict__ rowptr,
                                               int* __restrict__ bsum, int n) {
    __shared__ int lds[256];
    int t = threadIdx.x;
    int idx = blockIdx.x * 256 + t;
    int v = (idx < n) ? hist[idx] : 0;
    lds[t] = v; __syncthreads();
    for (int off = 1; off < 256; off <<= 1) {
        int x = (t >= off) ? lds[t - off] : 0;
        __syncthreads();
        lds[t] += x;
        __syncthreads();
    }
    if (idx < n) rowptr[idx] = lds[t] - v;
    if (t == 255) bsum[blockIdx.x] = lds[255];
}

__global__ __launch_bounds__(256) void k_scan2(const int* __restrict__ bsum,
                                               int* __restrict__ boff, int nb,
                                               int* __restrict__ rowptr, int n) {
    __shared__ int lds[256];
    int t = threadIdx.x;
    int carry = 0;
    for (int base = 0; base < nb; base += 256) {
        int v = (base + t < nb) ? bsum[base + t] : 0;
        lds[t] = v; __syncthreads();
        for (int off = 1; off < 256; off <<= 1) {
            int x = (t >= off) ? lds[t - off] : 0;
            __syncthreads();
            lds[t] += x;
            __syncthreads();
        }
        if (base + t < nb) boff[base + t] = carry + lds[t] - v;
        carry += lds[255];
        __syncthreads();
    }
    if (t == 0) rowptr[n] = carry;
}

__global__ void k_scan3(int* __restrict__ rowptr, const int* __restrict__ boff, int n) {
    int i = blockIdx.x * 256 + threadIdx.x;
    if (i < n) rowptr[i] += boff[blockIdx.x];
}

// place edges col-sorted, storing {row, ew} — NO atomics (slot precomputed)
__global__ void k_place(const int* __restrict__ row, const int* __restrict__ col,
                        const float* __restrict__ ew, const int* __restrict__ rowptr,
                        const int* __restrict__ pos, int2* __restrict__ pairs, int E) {
    int e = blockIdx.x * 256 + threadIdx.x;
    if (e >= E) return;
    int c = col[e];
    int slot = rowptr[c] + pos[e];
    pairs[slot] = make_int2(row[e], __float_as_int(ew[e]));
}

// dinv[g] = rsqrt(1 + sum ew over g's segment) — 4 lanes per node
__global__ void k_deg(const int2* __restrict__ pairs, const int* __restrict__ rowptr,
                      float* __restrict__ dinv, int n) {
    int t = blockIdx.x * 256 + threadIdx.x;
    int g = t >> 2, sub = t & 3;
    if (g >= n) return;
    int s = rowptr[g], e = rowptr[g + 1];
    float acc = 0.f;
    for (int i = s + sub; i < e; i += 4) acc += __int_as_float(pairs[i].y);
    acc += __shfl_xor(acc, 1, 4);
    acc += __shfl_xor(acc, 2, 4);
    if (sub == 0) dinv[g] = rsqrtf(1.f + acc);
}

// pairs.y: ew -> dinv[row]*ew (dest-side d applied in aggregate epilogue)
__global__ void k_premul(int2* __restrict__ pairs, const float* __restrict__ dinv, int E) {
    int e = blockIdx.x * 256 + threadIdx.x;
    if (e >= E) return;
    int2 p = pairs[e];
    pairs[e] = make_int2(p.x, __float_as_int(dinv[p.x] * __int_as_float(p.y)));
}

// x f32 -> bf16 (n*64 elems, 4 per thread)
__global__ void k_xbf(const float* __restrict__ x, unsigned short* __restrict__ xb,
                      long total4) {
    long i = (long)blockIdx.x * 256 + threadIdx.x;
    if (i >= total4) return;
    float4 v = reinterpret_cast<const float4*>(x)[i];
    ushort4 o;
    o.x = (unsigned short)f2bf_bits(v.x);
    o.y = (unsigned short)f2bf_bits(v.y);
    o.z = (unsigned short)f2bf_bits(v.z);
    o.w = (unsigned short)f2bf_bits(v.w);
    reinterpret_cast<ushort4*>(xb)[i] = o;
}

// ---------------- weight prep: all weights, one launch ----------------
__global__ void k_wtall(const float* __restrict__ W_in, const float* __restrict__ W_hid,
                        const float* __restrict__ W_out,
                        unsigned short* __restrict__ wt_in,
                        unsigned short* __restrict__ wt_hid,
                        unsigned short* __restrict__ wt_out) {
    int i = blockIdx.x * 256 + threadIdx.x;
    if (i < 8192) {                       // W_in: K=64, N=128
        int k = i / 128, nn = i % 128;
        wt_in[nn * 64 + k] = (unsigned short)f2bf_bits(W_in[i]);
    } else if (i < 73728) {               // W_hid: 4 x (K=128, N=128)
        int j = i - 8192;
        int l = j >> 14, r = j & 16383;
        int k = r / 128, nn = r % 128;
        wt_hid[l * 16384 + nn * 128 + k] = (unsigned short)f2bf_bits(W_hid[j]);
    } else if (i < 81920) {               // W_out: K=128, N=64
        int j = i - 73728;
        int k = j / 64, nn = j % 64;
        wt_out[nn * 128 + k] = (unsigned short)f2bf_bits(W_out[j]);
    }
}

// ---------------- MFMA GEMM: H = X @ W (+bias, relu if EPI) ---------------
// 128-row tile, 256 threads = 4 waves. LDS XOR-swizzled (byte ^= (row&7)<<4).
template <int K, int N, bool IN_BF16, bool EPI>
__global__ __launch_bounds__(256, 2) void k_gemm_mfma(
    const void* __restrict__ Xv, const unsigned short* __restrict__ Wt,
    const float* __restrict__ bias, unsigned short* __restrict__ H, int n)
{
    constexpr int NREP = N / 16;
    constexpr int KC   = K / 8;          // 16B chunks per row
    __shared__ char lds[128 * K * 2 + N * K * 2];
    char* Xs = lds;
    char* Ws = lds + 128 * K * 2;

    const int row0 = blockIdx.x * 128;
    const int tid  = threadIdx.x;

    for (int c = tid; c < 128 * KC; c += 256) {
        int r = c / KC, kc = c % KC;
        int gr = row0 + r;
        bf16x8 v = {0, 0, 0, 0, 0, 0, 0, 0};
        if (gr < n) {
            if constexpr (IN_BF16) {
                v = *(const bf16x8*)((const unsigned short*)Xv + (size_t)gr * K + kc * 8);
            } else {
                const float* xp = (const float*)Xv + (size_t)gr * K + kc * 8;
                float4 a = *(const float4*)xp;
                float4 b = *(const float4*)(xp + 4);
                v[0] = (short)f2bf_bits(a.x); v[1] = (short)f2bf_bits(a.y);
                v[2] = (short)f2bf_bits(a.z); v[3] = (short)f2bf_bits(a.w);
                v[4] = (short)f2bf_bits(b.x); v[5] = (short)f2bf_bits(b.y);
                v[6] = (short)f2bf_bits(b.z); v[7] = (short)f2bf_bits(b.w);
            }
        }
        *(bf16x8*)(Xs + ((r * (K * 2) + kc * 16) ^ ((r & 7) << 4))) = v;
    }
    for (int c = tid; c < N * KC; c += 256) {
        int r = c / KC, kc = c % KC;
        bf16x8 v = *(const bf16x8*)(Wt + (size_t)r * K + kc * 8);
        *(bf16x8*)(Ws + ((r * (K * 2) + kc * 16) ^ ((r & 7) << 4))) = v;
    }
    __syncthreads();

    const int wv   = tid >> 6;
    const int lane = tid & 63;
    const int lr   = lane & 15;
    const int lk   = lane >> 4;

    f32x4 acc[2][NREP];
    #pragma unroll
    for (int m = 0; m < 2; m++)
        #pragma unroll
        for (int j = 0; j < NREP; j++)
            acc[m][j] = (f32x4){0.f, 0.f, 0.f, 0.f};

    #pragma unroll
    for (int kk = 0; kk < K / 32; kk++) {
        int kc = kk * 4 + lk;
        bf16x8 af[2];
        #pragma unroll
        for (int m = 0; m < 2; m++) {
            int r = wv * 32 + m * 16 + lr;
            af[m] = *(const bf16x8*)(Xs + ((r * (K * 2) + kc * 16) ^ ((r & 7) << 4)));
        }
        #pragma unroll
        for (int j = 0; j < NREP; j++) {
            int r = j * 16 + lr;
            bf16x8 bfr = *(const bf16x8*)(Ws + ((r * (K * 2) + kc * 16) ^ ((r & 7) << 4)));
            acc[0][j] = __builtin_amdgcn_mfma_f32_16x16x32_bf16(af[0], bfr, acc[0][j], 0, 0, 0);
            acc[1][j] = __builtin_amdgcn_mfma_f32_16x16x32_bf16(af[1], bfr, acc[1][j], 0, 0, 0);
        }
    }

    #pragma unroll
    for (int m = 0; m < 2; m++) {
        #pragma unroll
        for (int j = 0; j < NREP; j++) {
            float bcol = EPI ? bias[j * 16 + lr] : 0.f;
            #pragma unroll
            for (int rr = 0; rr < 4; rr++) {
                int gr = row0 + wv * 32 + m * 16 + lk * 4 + rr;
                if (gr < n) {
                    float v = acc[m][j][rr];
                    if constexpr (EPI) v = fmaxf(v + bcol, 0.f);
                    H[(size_t)gr * N + j * 16 + lr] = (unsigned short)f2bf_bits(v);
                }
            }
        }
    }
}

// ---------------- gather-aggregate (128ch): premul pairs, pipelined -------
// Out[c] = act( d*( d*H[c] + sum_e p.y*H[row[e]] ) + b )
template <bool RELU>
__global__ __launch_bounds__(256) void k_aggregate128(
    const unsigned short* __restrict__ H, const int2* __restrict__ pairs,
    const int* __restrict__ rowptr, const float* __restrict__ dinv,
    const float* __restrict__ bias, unsigned* __restrict__ Out, int n)
{
    const int lane = threadIdx.x & 63;
    const int w    = threadIdx.x >> 6;
    int nd = blockIdx.x * 4 + w;
    if (nd >= n) return;
    int s  = rowptr[nd];
    int en = rowptr[nd + 1];
    float d = dinv[nd];

    const unsigned* Hu = (const unsigned*)H;
    unsigned sw = Hu[(size_t)nd * 64 + lane];
    float ax = d * bflo(sw), ay = d * bfhi(sw);

    int e = s;
    int2 ppA[8];
    bool haveA = (e + 8 <= en);
    if (haveA) {
        #pragma unroll
        for (int u = 0; u < 8; u++) ppA[u] = pairs[e + u];
    }
    while (haveA) {
        int enext = e + 8;
        int2 ppB[8];
        bool haveB = (enext + 8 <= en);
        if (haveB) {                        // prefetch next block early
            #pragma unroll
            for (int u = 0; u < 8; u++) ppB[u] = pairs[enext + u];
        }
        unsigned gv[8];
        #pragma unroll
        for (int u = 0; u < 8; u++) gv[u] = Hu[(size_t)ppA[u].x * 64 + lane];
        #pragma unroll
        for (int u = 0; u < 8; u++) {
            float nm = __int_as_float(ppA[u].y);
            ax = fmaf(nm, bflo(gv[u]), ax);
            ay = fmaf(nm, bfhi(gv[u]), ay);
        }
        #pragma unroll
        for (int u = 0; u < 8; u++) ppA[u] = ppB[u];
        e = enext; haveA = haveB;
    }
    for (; e < en; e++) {
        int2 p = pairs[e];
        unsigned g = Hu[(size_t)p.x * 64 + lane];
        float nm = __int_as_float(p.y);
        ax = fmaf(nm, bflo(g), ax);
        ay = fmaf(nm, bfhi(g), ay);
    }
    float2 bb = reinterpret_cast<const float2*>(bias)[lane];
    ax = d * ax + bb.x;
    ay = d * ay + bb.y;
    if (RELU) { ax = fmaxf(ax, 0.f); ay = fmaxf(ay, 0.f); }
    Out[(size_t)nd * 64 + lane] = f2bf_bits(ax) | (f2bf_bits(ay) << 16);
}

// ---------------- gather-aggregate (64ch): 2 nodes/wave, bf16 out ---------
// BIAS=false: pure T = A_hat@X (layer-1 input aggregation).
// BIAS=true : output layer (bias, no relu).
template <bool BIAS>
__global__ __launch_bounds__(256) void k_aggregate64(
    const unsigned short* __restrict__ H, const int2* __restrict__ pairs,
    const int* __restrict__ rowptr, const float* __restrict__ dinv,
    const float* __restrict__ bias, unsigned* __restrict__ Out, int n)
{
    const int lane = threadIdx.x & 63;
    const int w    = threadIdx.x >> 6;
    const int li   = lane & 31;                 // uint index within row
    int nd = (blockIdx.x * 4 + w) * 2 + (lane >> 5);
    if (nd >= n) return;
    int s  = rowptr[nd];
    int en = rowptr[nd + 1];
    float d = dinv[nd];

    const unsigned* Hu = (const unsigned*)H;    // 32 uints per row
    unsigned sw = Hu[(size_t)nd * 32 + li];
    float ax = d * bflo(sw), ay = d * bfhi(sw);

    int e = s;
    int2 ppA[8];
    bool haveA = (e + 8 <= en);
    if (haveA) {
        #pragma unroll
        for (int u = 0; u < 8; u++) ppA[u] = pairs[e + u];
    }
    while (haveA) {
        int enext = e + 8;
        int2 ppB[8];
        bool haveB = (enext + 8 <= en);
        if (haveB) {
            #pragma unroll
            for (int u = 0; u < 8; u++) ppB[u] = pairs[enext + u];
        }
        unsigned gv[8];
        #pragma unroll
        for (int u = 0; u < 8; u++) gv[u] = Hu[(size_t)ppA[u].x * 32 + li];
        #pragma unroll
        for (int u = 0; u < 8; u++) {
            float nm = __int_as_float(ppA[u].y);
            ax = fmaf(nm, bflo(gv[u]), ax);
            ay = fmaf(nm, bfhi(gv[u]), ay);
        }
        #pragma unroll
        for (int u = 0; u < 8; u++) ppA[u] = ppB[u];
        e = enext; haveA = haveB;
    }
    for (; e < en; e++) {
        int2 p = pairs[e];
        unsigned g = Hu[(size_t)p.x * 32 + li];
        float nm = __int_as_float(p.y);
        ax = fmaf(nm, bflo(g), ax);
        ay = fmaf(nm, bfhi(g), ay);
    }
    if constexpr (BIAS) {
        float2 bb = reinterpret_cast<const float2*>(bias)[li];
        ax = d * ax + bb.x;
        ay = d * ay + bb.y;
    } else {
        ax = d * ax;
        ay = d * ay;
    }
    Out[(size_t)nd * 32 + li] = f2bf_bits(ax) | (f2bf_bits(ay) << 16);
}

// logits = sigmoid(dot(enc[a], enc[b])) — 8 lanes/pair, bf16 enc (128B rows)
__global__ void k_decode(const unsigned short* __restrict__ enc,
                         const int* __restrict__ eli, int M, float* __restrict__ out)
{
    int gid  = blockIdx.x * 256 + threadIdx.x;
    int pair = gid >> 3;
    int l    = gid & 7;
    if (pair >= M) return;
    int a = eli[pair];
    int b = eli[M + pair];
    const uint4* E4 = (const uint4*)enc;        // 8 uint4 per 64-ch row
    uint4 va = E4[(size_t)a * 8 + l];
    uint4 vb = E4[(size_t)b * 8 + l];
    float s = 0.f;
    s = fmaf(bflo(va.x), bflo(vb.x), s); s = fmaf(bfhi(va.x), bfhi(vb.x), s);
    s = fmaf(bflo(va.y), bflo(vb.y), s); s = fmaf(bfhi(va.y), bfhi(vb.y), s);
    s = fmaf(bflo(va.z), bflo(vb.z), s); s = fmaf(bfhi(va.z), bfhi(vb.z), s);
    s = fmaf(bflo(va.w), bflo(vb.w), s); s = fmaf(bfhi(va.w), bfhi(vb.w), s);
    s += __shfl_xor(s, 4, 8);
    s += __shfl_xor(s, 2, 8);
    s += __shfl_xor(s, 1, 8);
    if (l == 0) out[pair] = 1.f / (1.f + expf(-s));
}

extern "C" void kernel_launch(void* const* d_in, const int* in_sizes, int n_in,
                              void* d_out, int out_size, void* d_ws, size_t ws_size,
                              hipStream_t stream)
{
    const float* x     = (const float*)d_in[0];
    const int*   ei    = (const int*)d_in[1];
    const float* ew    = (const float*)d_in[2];
    const int*   eli   = (const int*)d_in[3];
    const float* W_in  = (const float*)d_in[4];
    const float* b_in  = (const float*)d_in[5];
    const float* W_hid = (const float*)d_in[6];
    const float* b_hid = (const float*)d_in[7];
    const float* W_out = (const float*)d_in[8];
    const float* b_out = (const float*)d_in[9];

    const int n = in_sizes[0] / 64;
    const int E = in_sizes[1] / 2;
    const int M = in_sizes[3] / 2;
    const int* row = ei;
    const int* col = ei + E;

    const int NB   = (n + 255) / 256;
    const int nb_E = (E + 255) / 256;
    const int gb   = (n + 127) / 128;
    const int ab   = (n + 3) / 4;

    // ---- workspace layout (256B-aligned regions) ----
    char* basep = (char*)d_ws;
    size_t off = 0;
    auto alloc = [&](size_t bytes) {
        char* p = basep + off; off = (off + bytes + 255) & ~(size_t)255; return p; };
    float* dinv   = (float*)alloc((size_t)n * 4);
    int*   hist   = (int*)  alloc((size_t)n * 4);
    int*   rowptr = (int*)  alloc((size_t)(n + 1) * 4);
    int*   pos    = (int*)  alloc((size_t)E * 4);
    int*   bsum   = (int*)  alloc(1024 * 4);
    int*   boff   = (int*)  alloc(1024 * 4);
    int2*  pairs  = (int2*) alloc((size_t)E * 8);
    unsigned short* wt_in  = (unsigned short*)alloc((size_t)128 * 64 * 2);
    unsigned short* wt_hid = (unsigned short*)alloc((size_t)4 * 128 * 128 * 2);
    unsigned short* wt_out = (unsigned short*)alloc((size_t)64 * 128 * 2);
    unsigned short* xb     = (unsigned short*)alloc((size_t)n * 64 * 2);   // x bf16
    unsigned short* Hbf    = (unsigned short*)alloc((size_t)n * 128 * 2);  // scratch
    unsigned short* Abf    = (unsigned short*)alloc((size_t)n * 128 * 2);  // activations
    unsigned short* enc    = (unsigned short*)alloc((size_t)n * 64 * 2);   // bf16 enc

    // ---- CSR build (atomics only in k_hist; place is atomic-free) ----
    k_zero<<<NB, 256, 0, stream>>>(hist, n);
    k_hist<<<nb_E, 256, 0, stream>>>(col, hist, pos, E);
    k_scan1<<<NB, 256, 0, stream>>>(hist, rowptr, bsum, n);
    k_scan2<<<1, 256, 0, stream>>>(bsum, boff, NB, rowptr, n);
    k_scan3<<<NB, 256, 0, stream>>>(rowptr, boff, n);
    k_place<<<nb_E, 256, 0, stream>>>(row, col, ew, rowptr, pos, pairs, E);
    k_deg<<<(n * 4 + 255) / 256, 256, 0, stream>>>(pairs, rowptr, dinv, n);
    k_premul<<<nb_E, 256, 0, stream>>>(pairs, dinv, E);

    // ---- prep: weights (one launch) + x -> bf16 ----
    k_wtall<<<320, 256, 0, stream>>>(W_in, W_hid, W_out, wt_in, wt_hid, wt_out);
    k_xbf<<<(int)(((long)n * 16 + 255) / 256), 256, 0, stream>>>(x, xb, (long)n * 16);

    // ---- layer 1 (aggregate-first): T = A_hat@x ; A1 = relu(T@W_in + b) ----
    k_aggregate64<false><<<(n + 7) / 8, 256, 0, stream>>>(
        xb, pairs, rowptr, dinv, nullptr, (unsigned*)Hbf, n);
    k_gemm_mfma<64, 128, true, true><<<gb, 256, 0, stream>>>(
        Hbf, wt_in, b_in, Abf, n);

    // ---- 4 hidden layers: 128 -> 128 ----
    for (int i = 0; i < 4; i++) {
        k_gemm_mfma<128, 128, true, false><<<gb, 256, 0, stream>>>(
            Abf, wt_hid + (size_t)i * 128 * 128, nullptr, Hbf, n);
        k_aggregate128<true><<<ab, 256, 0, stream>>>(
            Hbf, pairs, rowptr, dinv, b_hid + (size_t)i * 128, (unsigned*)Abf, n);
    }

    // ---- output layer: 128 -> 64 ----
    k_gemm_mfma<128, 64, true, false><<<gb, 256, 0, stream>>>(
        Abf, wt_out, nullptr, Hbf, n);
    k_aggregate64<true><<<(n + 7) / 8, 256, 0, stream>>>(
        Hbf, pairs, rowptr, dinv, b_out, (unsigned*)enc, n);

    // ---- decoder ----
    k_decode<<<(M * 8 + 255) / 256, 256, 0, stream>>>(enc, eli, M, (float*)d_out);
}

// Round 12
// 645.402 us; speedup vs baseline: 1.1248x; 1.1248x over previous
//
#include <hip/hip_runtime.h>
#include <hip/hip_bf16.h>
#include <math.h>

// ---------------------------------------------------------------------------
// GCN link-prediction encoder: 6 GCN layers + dot-product decoder.
// R12 = R11 minus the manual gather pipeline (it cost 12us/dispatch via
// VGPR pressure + defeated compiler scheduling). Keeps: premul pairs
// (no dependent dinv gather), layer-1 aggregate-first, atomic-free place,
// single-launch weight prep. Gather loop = R10's simple 8-deep unroll.
// ---------------------------------------------------------------------------

using bf16x8 = __attribute__((ext_vector_type(8))) short;  // 8 bf16 = 4 VGPRs
using f32x4  = __attribute__((ext_vector_type(4))) float;

__device__ inline unsigned f2bf_bits(float f) {            // RNE f32 -> bf16
    unsigned u = __float_as_uint(f);
    return (u + 0x7fffu + ((u >> 16) & 1u)) >> 16;
}
__device__ inline float bflo(unsigned w) { return __uint_as_float(w << 16); }
__device__ inline float bfhi(unsigned w) { return __uint_as_float(w & 0xffff0000u); }

// ---------------- CSR build (int-only atomics) ----------------

__global__ void k_zero(int* __restrict__ hist, int n) {
    int i = blockIdx.x * 256 + threadIdx.x;
    if (i < n) hist[i] = 0;
}

// histogram + per-edge slot reservation (fetch-add return)
__global__ void k_hist(const int* __restrict__ col, int* __restrict__ hist,
                       int* __restrict__ pos, int E) {
    int i = blockIdx.x * 256 + threadIdx.x;
    if (i < E) pos[i] = atomicAdd(&hist[col[i]], 1);
}

__global__ __launch_bounds__(256) void k_scan1(const int* __restrict__ hist,
                                               int* __restrict__ rowptr,
                                               int* __restrict__ bsum, int n) {
    __shared__ int lds[256];
    int t = threadIdx.x;
    int idx = blockIdx.x * 256 + t;
    int v = (idx < n) ? hist[idx] : 0;
    lds[t] = v; __syncthreads();
    for (int off = 1; off < 256; off <<= 1) {
        int x = (t >= off) ? lds[t - off] : 0;
        __syncthreads();
        lds[t] += x;
        __syncthreads();
    }
    if (idx < n) rowptr[idx] = lds[t] - v;
    if (t == 255) bsum[blockIdx.x] = lds[255];
}

__global__ __launch_bounds__(256) void k_scan2(const int* __restrict__ bsum,
                                               int* __restrict__ boff, int nb,
                                               int* __restrict__ rowptr, int n) {
    __shared__ int lds[256];
    int t = threadIdx.x;
    int carry = 0;
    for (int base = 0; base < nb; base += 256) {
        int v = (base + t < nb) ? bsum[base + t] : 0;
        lds[t] = v; __syncthreads();
        for (int off = 1; off < 256; off <<= 1) {
            int x = (t >= off) ? lds[t - off] : 0;
            __syncthreads();
            lds[t] += x;
            __syncthreads();
        }
        if (base + t < nb) boff[base + t] = carry + lds[t] - v;
        carry += lds[255];
        __syncthreads();
    }
    if (t == 0) rowptr[n] = carry;
}

__global__ void k_scan3(int* __restrict__ rowptr, const int* __restrict__ boff, int n) {
    int i = blockIdx.x * 256 + threadIdx.x;
    if (i < n) rowptr[i] += boff[blockIdx.x];
}

// place edges col-sorted, storing {row, ew} — NO atomics (slot precomputed)
__global__ void k_place(const int* __restrict__ row, const int* __restrict__ col,
                        const float* __restrict__ ew, const int* __restrict__ rowptr,
                        const int* __restrict__ pos, int2* __restrict__ pairs, int E) {
    int e = blockIdx.x * 256 + threadIdx.x;
    if (e >= E) return;
    int c = col[e];
    int slot = rowptr[c] + pos[e];
    pairs[slot] = make_int2(row[e], __float_as_int(ew[e]));
}

// dinv[g] = rsqrt(1 + sum ew over g's segment) — 4 lanes per node
__global__ void k_deg(const int2* __restrict__ pairs, const int* __restrict__ rowptr,
                      float* __restrict__ dinv, int n) {
    int t = blockIdx.x * 256 + threadIdx.x;
    int g = t >> 2, sub = t & 3;
    if (g >= n) return;
    int s = rowptr[g], e = rowptr[g + 1];
    float acc = 0.f;
    for (int i = s + sub; i < e; i += 4) acc += __int_as_float(pairs[i].y);
    acc += __shfl_xor(acc, 1, 4);
    acc += __shfl_xor(acc, 2, 4);
    if (sub == 0) dinv[g] = rsqrtf(1.f + acc);
}

// pairs.y: ew -> dinv[row]*ew (dest-side d applied in aggregate epilogue)
__global__ void k_premul(int2* __restrict__ pairs, const float* __restrict__ dinv, int E) {
    int e = blockIdx.x * 256 + threadIdx.x;
    if (e >= E) return;
    int2 p = pairs[e];
    pairs[e] = make_int2(p.x, __float_as_int(dinv[p.x] * __int_as_float(p.y)));
}

// x f32 -> bf16 (4 per thread)
__global__ void k_xbf(const float* __restrict__ x, unsigned short* __restrict__ xb,
                      long total4) {
    long i = (long)blockIdx.x * 256 + threadIdx.x;
    if (i >= total4) return;
    float4 v = reinterpret_cast<const float4*>(x)[i];
    ushort4 o;
    o.x = (unsigned short)f2bf_bits(v.x);
    o.y = (unsigned short)f2bf_bits(v.y);
    o.z = (unsigned short)f2bf_bits(v.z);
    o.w = (unsigned short)f2bf_bits(v.w);
    reinterpret_cast<ushort4*>(xb)[i] = o;
}

// ---------------- weight prep: all weights, one launch ----------------
__global__ void k_wtall(const float* __restrict__ W_in, const float* __restrict__ W_hid,
                        const float* __restrict__ W_out,
                        unsigned short* __restrict__ wt_in,
                        unsigned short* __restrict__ wt_hid,
                        unsigned short* __restrict__ wt_out) {
    int i = blockIdx.x * 256 + threadIdx.x;
    if (i < 8192) {                       // W_in: K=64, N=128
        int k = i / 128, nn = i % 128;
        wt_in[nn * 64 + k] = (unsigned short)f2bf_bits(W_in[i]);
    } else if (i < 73728) {               // W_hid: 4 x (K=128, N=128)
        int j = i - 8192;
        int l = j >> 14, r = j & 16383;
        int k = r / 128, nn = r % 128;
        wt_hid[l * 16384 + nn * 128 + k] = (unsigned short)f2bf_bits(W_hid[j]);
    } else if (i < 81920) {               // W_out: K=128, N=64
        int j = i - 73728;
        int k = j / 64, nn = j % 64;
        wt_out[nn * 128 + k] = (unsigned short)f2bf_bits(W_out[j]);
    }
}

// ---------------- MFMA GEMM: H = X @ W (+bias, relu if EPI) ---------------
// 128-row tile, 256 threads = 4 waves. LDS XOR-swizzled (byte ^= (row&7)<<4).
template <int K, int N, bool IN_BF16, bool EPI>
__global__ __launch_bounds__(256, 2) void k_gemm_mfma(
    const void* __restrict__ Xv, const unsigned short* __restrict__ Wt,
    const float* __restrict__ bias, unsigned short* __restrict__ H, int n)
{
    constexpr int NREP = N / 16;
    constexpr int KC   = K / 8;          // 16B chunks per row
    __shared__ char lds[128 * K * 2 + N * K * 2];
    char* Xs = lds;
    char* Ws = lds + 128 * K * 2;

    const int row0 = blockIdx.x * 128;
    const int tid  = threadIdx.x;

    for (int c = tid; c < 128 * KC; c += 256) {
        int r = c / KC, kc = c % KC;
        int gr = row0 + r;
        bf16x8 v = {0, 0, 0, 0, 0, 0, 0, 0};
        if (gr < n) {
            if constexpr (IN_BF16) {
                v = *(const bf16x8*)((const unsigned short*)Xv + (size_t)gr * K + kc * 8);
            } else {
                const float* xp = (const float*)Xv + (size_t)gr * K + kc * 8;
                float4 a = *(const float4*)xp;
                float4 b = *(const float4*)(xp + 4);
                v[0] = (short)f2bf_bits(a.x); v[1] = (short)f2bf_bits(a.y);
                v[2] = (short)f2bf_bits(a.z); v[3] = (short)f2bf_bits(a.w);
                v[4] = (short)f2bf_bits(b.x); v[5] = (short)f2bf_bits(b.y);
                v[6] = (short)f2bf_bits(b.z); v[7] = (short)f2bf_bits(b.w);
            }
        }
        *(bf16x8*)(Xs + ((r * (K * 2) + kc * 16) ^ ((r & 7) << 4))) = v;
    }
    for (int c = tid; c < N * KC; c += 256) {
        int r = c / KC, kc = c % KC;
        bf16x8 v = *(const bf16x8*)(Wt + (size_t)r * K + kc * 8);
        *(bf16x8*)(Ws + ((r * (K * 2) + kc * 16) ^ ((r & 7) << 4))) = v;
    }
    __syncthreads();

    const int wv   = tid >> 6;
    const int lane = tid & 63;
    const int lr   = lane & 15;
    const int lk   = lane >> 4;

    f32x4 acc[2][NREP];
    #pragma unroll
    for (int m = 0; m < 2; m++)
        #pragma unroll
        for (int j = 0; j < NREP; j++)
            acc[m][j] = (f32x4){0.f, 0.f, 0.f, 0.f};

    #pragma unroll
    for (int kk = 0; kk < K / 32; kk++) {
        int kc = kk * 4 + lk;
        bf16x8 af[2];
        #pragma unroll
        for (int m = 0; m < 2; m++) {
            int r = wv * 32 + m * 16 + lr;
            af[m] = *(const bf16x8*)(Xs + ((r * (K * 2) + kc * 16) ^ ((r & 7) << 4)));
        }
        #pragma unroll
        for (int j = 0; j < NREP; j++) {
            int r = j * 16 + lr;
            bf16x8 bfr = *(const bf16x8*)(Ws + ((r * (K * 2) + kc * 16) ^ ((r & 7) << 4)));
            acc[0][j] = __builtin_amdgcn_mfma_f32_16x16x32_bf16(af[0], bfr, acc[0][j], 0, 0, 0);
            acc[1][j] = __builtin_amdgcn_mfma_f32_16x16x32_bf16(af[1], bfr, acc[1][j], 0, 0, 0);
        }
    }

    #pragma unroll
    for (int m = 0; m < 2; m++) {
        #pragma unroll
        for (int j = 0; j < NREP; j++) {
            float bcol = EPI ? bias[j * 16 + lr] : 0.f;
            #pragma unroll
            for (int rr = 0; rr < 4; rr++) {
                int gr = row0 + wv * 32 + m * 16 + lk * 4 + rr;
                if (gr < n) {
                    float v = acc[m][j][rr];
                    if constexpr (EPI) v = fmaxf(v + bcol, 0.f);
                    H[(size_t)gr * N + j * 16 + lr] = (unsigned short)f2bf_bits(v);
                }
            }
        }
    }
}

// ---------------- gather-aggregate (128ch): premul pairs, simple loop -----
// Out[c] = act( d*( d*H[c] + sum_e p.y*H[row[e]] ) + b )
template <bool RELU>
__global__ __launch_bounds__(256) void k_aggregate128(
    const unsigned short* __restrict__ H, const int2* __restrict__ pairs,
    const int* __restrict__ rowptr, const float* __restrict__ dinv,
    const float* __restrict__ bias, unsigned* __restrict__ Out, int n)
{
    const int lane = threadIdx.x & 63;
    const int w    = threadIdx.x >> 6;
    int nd = blockIdx.x * 4 + w;
    if (nd >= n) return;
    int s  = rowptr[nd];
    int en = rowptr[nd + 1];
    float d = dinv[nd];

    const unsigned* Hu = (const unsigned*)H;
    unsigned sw = Hu[(size_t)nd * 64 + lane];
    float ax = d * bflo(sw), ay = d * bfhi(sw);
    int e = s;
    for (; e + 8 <= en; e += 8) {               // 8-deep, compiler-scheduled
        int2 pp[8]; unsigned gv[8];
        #pragma unroll
        for (int u = 0; u < 8; u++) pp[u] = pairs[e + u];
        #pragma unroll
        for (int u = 0; u < 8; u++) gv[u] = Hu[(size_t)pp[u].x * 64 + lane];
        #pragma unroll
        for (int u = 0; u < 8; u++) {
            float nm = __int_as_float(pp[u].y);
            ax = fmaf(nm, bflo(gv[u]), ax);
            ay = fmaf(nm, bfhi(gv[u]), ay);
        }
    }
    for (; e < en; e++) {
        int2 p = pairs[e];
        unsigned g = Hu[(size_t)p.x * 64 + lane];
        float nm = __int_as_float(p.y);
        ax = fmaf(nm, bflo(g), ax);
        ay = fmaf(nm, bfhi(g), ay);
    }
    float2 bb = reinterpret_cast<const float2*>(bias)[lane];
    ax = d * ax + bb.x;
    ay = d * ay + bb.y;
    if (RELU) { ax = fmaxf(ax, 0.f); ay = fmaxf(ay, 0.f); }
    Out[(size_t)nd * 64 + lane] = f2bf_bits(ax) | (f2bf_bits(ay) << 16);
}

// ---------------- gather-aggregate (64ch): 2 nodes/wave, bf16 out ---------
// BIAS=false: pure T = A_hat@X (layer-1 input aggregation).
// BIAS=true : output layer (bias, no relu).
template <bool BIAS>
__global__ __launch_bounds__(256) void k_aggregate64(
    const unsigned short* __restrict__ H, const int2* __restrict__ pairs,
    const int* __restrict__ rowptr, const float* __restrict__ dinv,
    const float* __restrict__ bias, unsigned* __restrict__ Out, int n)
{
    const int lane = threadIdx.x & 63;
    const int w    = threadIdx.x >> 6;
    const int li   = lane & 31;                 // uint index within row
    int nd = (blockIdx.x * 4 + w) * 2 + (lane >> 5);
    if (nd >= n) return;
    int s  = rowptr[nd];
    int en = rowptr[nd + 1];
    float d = dinv[nd];

    const unsigned* Hu = (const unsigned*)H;    // 32 uints per row
    unsigned sw = Hu[(size_t)nd * 32 + li];
    float ax = d * bflo(sw), ay = d * bfhi(sw);
    int e = s;
    for (; e + 8 <= en; e += 8) {
        int2 pp[8]; unsigned gv[8];
        #pragma unroll
        for (int u = 0; u < 8; u++) pp[u] = pairs[e + u];
        #pragma unroll
        for (int u = 0; u < 8; u++) gv[u] = Hu[(size_t)pp[u].x * 32 + li];
        #pragma unroll
        for (int u = 0; u < 8; u++) {
            float nm = __int_as_float(pp[u].y);
            ax = fmaf(nm, bflo(gv[u]), ax);
            ay = fmaf(nm, bfhi(gv[u]), ay);
        }
    }
    for (; e < en; e++) {
        int2 p = pairs[e];
        unsigned g = Hu[(size_t)p.x * 32 + li];
        float nm = __int_as_float(p.y);
        ax = fmaf(nm, bflo(g), ax);
        ay = fmaf(nm, bfhi(g), ay);
    }
    if constexpr (BIAS) {
        float2 bb = reinterpret_cast<const float2*>(bias)[li];
        ax = d * ax + bb.x;
        ay = d * ay + bb.y;
    } else {
        ax = d * ax;
        ay = d * ay;
    }
    Out[(size_t)nd * 32 + li] = f2bf_bits(ax) | (f2bf_bits(ay) << 16);
}

// logits = sigmoid(dot(enc[a], enc[b])) — 8 lanes/pair, bf16 enc (128B rows)
__global__ void k_decode(const unsigned short* __restrict__ enc,
                         const int* __restrict__ eli, int M, float* __restrict__ out)
{
    int gid  = blockIdx.x * 256 + threadIdx.x;
    int pair = gid >> 3;
    int l    = gid & 7;
    if (pair >= M) return;
    int a = eli[pair];
    int b = eli[M + pair];
    const uint4* E4 = (const uint4*)enc;        // 8 uint4 per 64-ch row
    uint4 va = E4[(size_t)a * 8 + l];
    uint4 vb = E4[(size_t)b * 8 + l];
    float s = 0.f;
    s = fmaf(bflo(va.x), bflo(vb.x), s); s = fmaf(bfhi(va.x), bfhi(vb.x), s);
    s = fmaf(bflo(va.y), bflo(vb.y), s); s = fmaf(bfhi(va.y), bfhi(vb.y), s);
    s = fmaf(bflo(va.z), bflo(vb.z), s); s = fmaf(bfhi(va.z), bfhi(vb.z), s);
    s = fmaf(bflo(va.w), bflo(vb.w), s); s = fmaf(bfhi(va.w), bfhi(vb.w), s);
    s += __shfl_xor(s, 4, 8);
    s += __shfl_xor(s, 2, 8);
    s += __shfl_xor(s, 1, 8);
    if (l == 0) out[pair] = 1.f / (1.f + expf(-s));
}

extern "C" void kernel_launch(void* const* d_in, const int* in_sizes, int n_in,
                              void* d_out, int out_size, void* d_ws, size_t ws_size,
                              hipStream_t stream)
{
    const float* x     = (const float*)d_in[0];
    const int*   ei    = (const int*)d_in[1];
    const float* ew    = (const float*)d_in[2];
    const int*   eli   = (const int*)d_in[3];
    const float* W_in  = (const float*)d_in[4];
    const float* b_in  = (const float*)d_in[5];
    const float* W_hid = (const float*)d_in[6];
    const float* b_hid = (const float*)d_in[7];
    const float* W_out = (const float*)d_in[8];
    const float* b_out = (const float*)d_in[9];

    const int n = in_sizes[0] / 64;
    const int E = in_sizes[1] / 2;
    const int M = in_sizes[3] / 2;
    const int* row = ei;
    const int* col = ei + E;

    const int NB   = (n + 255) / 256;
    const int nb_E = (E + 255) / 256;
    const int gb   = (n + 127) / 128;
    const int ab   = (n + 3) / 4;

    // ---- workspace layout (256B-aligned regions) ----
    char* basep = (char*)d_ws;
    size_t off = 0;
    auto alloc = [&](size_t bytes) {
        char* p = basep + off; off = (off + bytes + 255) & ~(size_t)255; return p; };
    float* dinv   = (float*)alloc((size_t)n * 4);
    int*   hist   = (int*)  alloc((size_t)n * 4);
    int*   rowptr = (int*)  alloc((size_t)(n + 1) * 4);
    int*   pos    = (int*)  alloc((size_t)E * 4);
    int*   bsum   = (int*)  alloc(1024 * 4);
    int*   boff   = (int*)  alloc(1024 * 4);
    int2*  pairs  = (int2*) alloc((size_t)E * 8);
    unsigned short* wt_in  = (unsigned short*)alloc((size_t)128 * 64 * 2);
    unsigned short* wt_hid = (unsigned short*)alloc((size_t)4 * 128 * 128 * 2);
    unsigned short* wt_out = (unsigned short*)alloc((size_t)64 * 128 * 2);
    unsigned short* xb     = (unsigned short*)alloc((size_t)n * 64 * 2);   // x bf16
    unsigned short* Hbf    = (unsigned short*)alloc((size_t)n * 128 * 2);  // scratch
    unsigned short* Abf    = (unsigned short*)alloc((size_t)n * 128 * 2);  // activations
    unsigned short* enc    = (unsigned short*)alloc((size_t)n * 64 * 2);   // bf16 enc

    // ---- CSR build (atomics only in k_hist; place is atomic-free) ----
    k_zero<<<NB, 256, 0, stream>>>(hist, n);
    k_hist<<<nb_E, 256, 0, stream>>>(col, hist, pos, E);
    k_scan1<<<NB, 256, 0, stream>>>(hist, rowptr, bsum, n);
    k_scan2<<<1, 256, 0, stream>>>(bsum, boff, NB, rowptr, n);
    k_scan3<<<NB, 256, 0, stream>>>(rowptr, boff, n);
    k_place<<<nb_E, 256, 0, stream>>>(row, col, ew, rowptr, pos, pairs, E);
    k_deg<<<(n * 4 + 255) / 256, 256, 0, stream>>>(pairs, rowptr, dinv, n);
    k_premul<<<nb_E, 256, 0, stream>>>(pairs, dinv, E);

    // ---- prep: weights (one launch) + x -> bf16 ----
    k_wtall<<<320, 256, 0, stream>>>(W_in, W_hid, W_out, wt_in, wt_hid, wt_out);
    k_xbf<<<(int)(((long)n * 16 + 255) / 256), 256, 0, stream>>>(x, xb, (long)n * 16);

    // ---- layer 1 (aggregate-first): T = A_hat@x ; A1 = relu(T@W_in + b) ----
    k_aggregate64<false><<<(n + 7) / 8, 256, 0, stream>>>(
        xb, pairs, rowptr, dinv, nullptr, (unsigned*)Hbf, n);
    k_gemm_mfma<64, 128, true, true><<<gb, 256, 0, stream>>>(
        Hbf, wt_in, b_in, Abf, n);

    // ---- 4 hidden layers: 128 -> 128 ----
    for (int i = 0; i < 4; i++) {
        k_gemm_mfma<128, 128, true, false><<<gb, 256, 0, stream>>>(
            Abf, wt_hid + (size_t)i * 128 * 128, nullptr, Hbf, n);
        k_aggregate128<true><<<ab, 256, 0, stream>>>(
            Hbf, pairs, rowptr, dinv, b_hid + (size_t)i * 128, (unsigned*)Abf, n);
    }

    // ---- output layer: 128 -> 64 ----
    k_gemm_mfma<128, 64, true, false><<<gb, 256, 0, stream>>>(
        Abf, wt_out, nullptr, Hbf, n);
    k_aggregate64<true><<<(n + 7) / 8, 256, 0, stream>>>(
        Hbf, pairs, rowptr, dinv, b_out, (unsigned*)enc, n);

    // ---- decoder ----
    k_decode<<<(M * 8 + 255) / 256, 256, 0, stream>>>(enc, eli, M, (float*)d_out);
}

// Round 13
// 618.109 us; speedup vs baseline: 1.1744x; 1.0442x over previous
//
#include <hip/hip_runtime.h>
#include <hip/hip_bf16.h>
#include <math.h>

// ---------------------------------------------------------------------------
// GCN link-prediction encoder: 6 GCN layers + dot-product decoder.
// R13 = R12 with k_aggregate128 gather depth 8 -> 12 (discriminating test:
// latency-bound vs fabric-throughput-bound). agg64 kept at 8-deep as the
// in-round control. All else frozen.
// ---------------------------------------------------------------------------

using bf16x8 = __attribute__((ext_vector_type(8))) short;  // 8 bf16 = 4 VGPRs
using f32x4  = __attribute__((ext_vector_type(4))) float;

__device__ inline unsigned f2bf_bits(float f) {            // RNE f32 -> bf16
    unsigned u = __float_as_uint(f);
    return (u + 0x7fffu + ((u >> 16) & 1u)) >> 16;
}
__device__ inline float bflo(unsigned w) { return __uint_as_float(w << 16); }
__device__ inline float bfhi(unsigned w) { return __uint_as_float(w & 0xffff0000u); }

// ---------------- CSR build (int-only atomics) ----------------

__global__ void k_zero(int* __restrict__ hist, int n) {
    int i = blockIdx.x * 256 + threadIdx.x;
    if (i < n) hist[i] = 0;
}

// histogram + per-edge slot reservation (fetch-add return)
__global__ void k_hist(const int* __restrict__ col, int* __restrict__ hist,
                       int* __restrict__ pos, int E) {
    int i = blockIdx.x * 256 + threadIdx.x;
    if (i < E) pos[i] = atomicAdd(&hist[col[i]], 1);
}

__global__ __launch_bounds__(256) void k_scan1(const int* __restrict__ hist,
                                               int* __restrict__ rowptr,
                                               int* __restrict__ bsum, int n) {
    __shared__ int lds[256];
    int t = threadIdx.x;
    int idx = blockIdx.x * 256 + t;
    int v = (idx < n) ? hist[idx] : 0;
    lds[t] = v; __syncthreads();
    for (int off = 1; off < 256; off <<= 1) {
        int x = (t >= off) ? lds[t - off] : 0;
        __syncthreads();
        lds[t] += x;
        __syncthreads();
    }
    if (idx < n) rowptr[idx] = lds[t] - v;
    if (t == 255) bsum[blockIdx.x] = lds[255];
}

__global__ __launch_bounds__(256) void k_scan2(const int* __restrict__ bsum,
                                               int* __restrict__ boff, int nb,
                                               int* __restrict__ rowptr, int n) {
    __shared__ int lds[256];
    int t = threadIdx.x;
    int carry = 0;
    for (int base = 0; base < nb; base += 256) {
        int v = (base + t < nb) ? bsum[base + t] : 0;
        lds[t] = v; __syncthreads();
        for (int off = 1; off < 256; off <<= 1) {
            int x = (t >= off) ? lds[t - off] : 0;
            __syncthreads();
            lds[t] += x;
            __syncthreads();
        }
        if (base + t < nb) boff[base + t] = carry + lds[t] - v;
        carry += lds[255];
        __syncthreads();
    }
    if (t == 0) rowptr[n] = carry;
}

__global__ void k_scan3(int* __restrict__ rowptr, const int* __restrict__ boff, int n) {
    int i = blockIdx.x * 256 + threadIdx.x;
    if (i < n) rowptr[i] += boff[blockIdx.x];
}

// place edges col-sorted, storing {row, ew} — NO atomics (slot precomputed)
__global__ void k_place(const int* __restrict__ row, const int* __restrict__ col,
                        const float* __restrict__ ew, const int* __restrict__ rowptr,
                        const int* __restrict__ pos, int2* __restrict__ pairs, int E) {
    int e = blockIdx.x * 256 + threadIdx.x;
    if (e >= E) return;
    int c = col[e];
    int slot = rowptr[c] + pos[e];
    pairs[slot] = make_int2(row[e], __float_as_int(ew[e]));
}

// dinv[g] = rsqrt(1 + sum ew over g's segment) — 4 lanes per node
__global__ void k_deg(const int2* __restrict__ pairs, const int* __restrict__ rowptr,
                      float* __restrict__ dinv, int n) {
    int t = blockIdx.x * 256 + threadIdx.x;
    int g = t >> 2, sub = t & 3;
    if (g >= n) return;
    int s = rowptr[g], e = rowptr[g + 1];
    float acc = 0.f;
    for (int i = s + sub; i < e; i += 4) acc += __int_as_float(pairs[i].y);
    acc += __shfl_xor(acc, 1, 4);
    acc += __shfl_xor(acc, 2, 4);
    if (sub == 0) dinv[g] = rsqrtf(1.f + acc);
}

// pairs.y: ew -> dinv[row]*ew (dest-side d applied in aggregate epilogue)
__global__ void k_premul(int2* __restrict__ pairs, const float* __restrict__ dinv, int E) {
    int e = blockIdx.x * 256 + threadIdx.x;
    if (e >= E) return;
    int2 p = pairs[e];
    pairs[e] = make_int2(p.x, __float_as_int(dinv[p.x] * __int_as_float(p.y)));
}

// x f32 -> bf16 (4 per thread)
__global__ void k_xbf(const float* __restrict__ x, unsigned short* __restrict__ xb,
                      long total4) {
    long i = (long)blockIdx.x * 256 + threadIdx.x;
    if (i >= total4) return;
    float4 v = reinterpret_cast<const float4*>(x)[i];
    ushort4 o;
    o.x = (unsigned short)f2bf_bits(v.x);
    o.y = (unsigned short)f2bf_bits(v.y);
    o.z = (unsigned short)f2bf_bits(v.z);
    o.w = (unsigned short)f2bf_bits(v.w);
    reinterpret_cast<ushort4*>(xb)[i] = o;
}

// ---------------- weight prep: all weights, one launch ----------------
__global__ void k_wtall(const float* __restrict__ W_in, const float* __restrict__ W_hid,
                        const float* __restrict__ W_out,
                        unsigned short* __restrict__ wt_in,
                        unsigned short* __restrict__ wt_hid,
                        unsigned short* __restrict__ wt_out) {
    int i = blockIdx.x * 256 + threadIdx.x;
    if (i < 8192) {                       // W_in: K=64, N=128
        int k = i / 128, nn = i % 128;
        wt_in[nn * 64 + k] = (unsigned short)f2bf_bits(W_in[i]);
    } else if (i < 73728) {               // W_hid: 4 x (K=128, N=128)
        int j = i - 8192;
        int l = j >> 14, r = j & 16383;
        int k = r / 128, nn = r % 128;
        wt_hid[l * 16384 + nn * 128 + k] = (unsigned short)f2bf_bits(W_hid[j]);
    } else if (i < 81920) {               // W_out: K=128, N=64
        int j = i - 73728;
        int k = j / 64, nn = j % 64;
        wt_out[nn * 128 + k] = (unsigned short)f2bf_bits(W_out[j]);
    }
}

// ---------------- MFMA GEMM: H = X @ W (+bias, relu if EPI) ---------------
// 128-row tile, 256 threads = 4 waves. LDS XOR-swizzled (byte ^= (row&7)<<4).
template <int K, int N, bool IN_BF16, bool EPI>
__global__ __launch_bounds__(256, 2) void k_gemm_mfma(
    const void* __restrict__ Xv, const unsigned short* __restrict__ Wt,
    const float* __restrict__ bias, unsigned short* __restrict__ H, int n)
{
    constexpr int NREP = N / 16;
    constexpr int KC   = K / 8;          // 16B chunks per row
    __shared__ char lds[128 * K * 2 + N * K * 2];
    char* Xs = lds;
    char* Ws = lds + 128 * K * 2;

    const int row0 = blockIdx.x * 128;
    const int tid  = threadIdx.x;

    for (int c = tid; c < 128 * KC; c += 256) {
        int r = c / KC, kc = c % KC;
        int gr = row0 + r;
        bf16x8 v = {0, 0, 0, 0, 0, 0, 0, 0};
        if (gr < n) {
            if constexpr (IN_BF16) {
                v = *(const bf16x8*)((const unsigned short*)Xv + (size_t)gr * K + kc * 8);
            } else {
                const float* xp = (const float*)Xv + (size_t)gr * K + kc * 8;
                float4 a = *(const float4*)xp;
                float4 b = *(const float4*)(xp + 4);
                v[0] = (short)f2bf_bits(a.x); v[1] = (short)f2bf_bits(a.y);
                v[2] = (short)f2bf_bits(a.z); v[3] = (short)f2bf_bits(a.w);
                v[4] = (short)f2bf_bits(b.x); v[5] = (short)f2bf_bits(b.y);
                v[6] = (short)f2bf_bits(b.z); v[7] = (short)f2bf_bits(b.w);
            }
        }
        *(bf16x8*)(Xs + ((r * (K * 2) + kc * 16) ^ ((r & 7) << 4))) = v;
    }
    for (int c = tid; c < N * KC; c += 256) {
        int r = c / KC, kc = c % KC;
        bf16x8 v = *(const bf16x8*)(Wt + (size_t)r * K + kc * 8);
        *(bf16x8*)(Ws + ((r * (K * 2) + kc * 16) ^ ((r & 7) << 4))) = v;
    }
    __syncthreads();

    const int wv   = tid >> 6;
    const int lane = tid & 63;
    const int lr   = lane & 15;
    const int lk   = lane >> 4;

    f32x4 acc[2][NREP];
    #pragma unroll
    for (int m = 0; m < 2; m++)
        #pragma unroll
        for (int j = 0; j < NREP; j++)
            acc[m][j] = (f32x4){0.f, 0.f, 0.f, 0.f};

    #pragma unroll
    for (int kk = 0; kk < K / 32; kk++) {
        int kc = kk * 4 + lk;
        bf16x8 af[2];
        #pragma unroll
        for (int m = 0; m < 2; m++) {
            int r = wv * 32 + m * 16 + lr;
            af[m] = *(const bf16x8*)(Xs + ((r * (K * 2) + kc * 16) ^ ((r & 7) << 4)));
        }
        #pragma unroll
        for (int j = 0; j < NREP; j++) {
            int r = j * 16 + lr;
            bf16x8 bfr = *(const bf16x8*)(Ws + ((r * (K * 2) + kc * 16) ^ ((r & 7) << 4)));
            acc[0][j] = __builtin_amdgcn_mfma_f32_16x16x32_bf16(af[0], bfr, acc[0][j], 0, 0, 0);
            acc[1][j] = __builtin_amdgcn_mfma_f32_16x16x32_bf16(af[1], bfr, acc[1][j], 0, 0, 0);
        }
    }

    #pragma unroll
    for (int m = 0; m < 2; m++) {
        #pragma unroll
        for (int j = 0; j < NREP; j++) {
            float bcol = EPI ? bias[j * 16 + lr] : 0.f;
            #pragma unroll
            for (int rr = 0; rr < 4; rr++) {
                int gr = row0 + wv * 32 + m * 16 + lk * 4 + rr;
                if (gr < n) {
                    float v = acc[m][j][rr];
                    if constexpr (EPI) v = fmaxf(v + bcol, 0.f);
                    H[(size_t)gr * N + j * 16 + lr] = (unsigned short)f2bf_bits(v);
                }
            }
        }
    }
}

// ---------------- gather-aggregate (128ch): premul pairs, 12-deep ---------
// Out[c] = act( d*( d*H[c] + sum_e p.y*H[row[e]] ) + b )
template <bool RELU>
__global__ __launch_bounds__(256) void k_aggregate128(
    const unsigned short* __restrict__ H, const int2* __restrict__ pairs,
    const int* __restrict__ rowptr, const float* __restrict__ dinv,
    const float* __restrict__ bias, unsigned* __restrict__ Out, int n)
{
    const int lane = threadIdx.x & 63;
    const int w    = threadIdx.x >> 6;
    int nd = blockIdx.x * 4 + w;
    if (nd >= n) return;
    int s  = rowptr[nd];
    int en = rowptr[nd + 1];
    float d = dinv[nd];

    const unsigned* Hu = (const unsigned*)H;
    unsigned sw = Hu[(size_t)nd * 64 + lane];
    float ax = d * bflo(sw), ay = d * bfhi(sw);
    int e = s;
    for (; e + 12 <= en; e += 12) {             // 12-deep, compiler-scheduled
        int2 pp[12]; unsigned gv[12];
        #pragma unroll
        for (int u = 0; u < 12; u++) pp[u] = pairs[e + u];
        #pragma unroll
        for (int u = 0; u < 12; u++) gv[u] = Hu[(size_t)pp[u].x * 64 + lane];
        #pragma unroll
        for (int u = 0; u < 12; u++) {
            float nm = __int_as_float(pp[u].y);
            ax = fmaf(nm, bflo(gv[u]), ax);
            ay = fmaf(nm, bfhi(gv[u]), ay);
        }
    }
    for (; e + 4 <= en; e += 4) {
        int2 pp[4]; unsigned gv[4];
        #pragma unroll
        for (int u = 0; u < 4; u++) pp[u] = pairs[e + u];
        #pragma unroll
        for (int u = 0; u < 4; u++) gv[u] = Hu[(size_t)pp[u].x * 64 + lane];
        #pragma unroll
        for (int u = 0; u < 4; u++) {
            float nm = __int_as_float(pp[u].y);
            ax = fmaf(nm, bflo(gv[u]), ax);
            ay = fmaf(nm, bfhi(gv[u]), ay);
        }
    }
    for (; e < en; e++) {
        int2 p = pairs[e];
        unsigned g = Hu[(size_t)p.x * 64 + lane];
        float nm = __int_as_float(p.y);
        ax = fmaf(nm, bflo(g), ax);
        ay = fmaf(nm, bfhi(g), ay);
    }
    float2 bb = reinterpret_cast<const float2*>(bias)[lane];
    ax = d * ax + bb.x;
    ay = d * ay + bb.y;
    if (RELU) { ax = fmaxf(ax, 0.f); ay = fmaxf(ay, 0.f); }
    Out[(size_t)nd * 64 + lane] = f2bf_bits(ax) | (f2bf_bits(ay) << 16);
}

// ---------------- gather-aggregate (64ch): 2 nodes/wave, 8-deep (control) -
// BIAS=false: pure T = A_hat@X (layer-1 input aggregation).
// BIAS=true : output layer (bias, no relu).
template <bool BIAS>
__global__ __launch_bounds__(256) void k_aggregate64(
    const unsigned short* __restrict__ H, const int2* __restrict__ pairs,
    const int* __restrict__ rowptr, const float* __restrict__ dinv,
    const float* __restrict__ bias, unsigned* __restrict__ Out, int n)
{
    const int lane = threadIdx.x & 63;
    const int w    = threadIdx.x >> 6;
    const int li   = lane & 31;                 // uint index within row
    int nd = (blockIdx.x * 4 + w) * 2 + (lane >> 5);
    if (nd >= n) return;
    int s  = rowptr[nd];
    int en = rowptr[nd + 1];
    float d = dinv[nd];

    const unsigned* Hu = (const unsigned*)H;    // 32 uints per row
    unsigned sw = Hu[(size_t)nd * 32 + li];
    float ax = d * bflo(sw), ay = d * bfhi(sw);
    int e = s;
    for (; e + 8 <= en; e += 8) {
        int2 pp[8]; unsigned gv[8];
        #pragma unroll
        for (int u = 0; u < 8; u++) pp[u] = pairs[e + u];
        #pragma unroll
        for (int u = 0; u < 8; u++) gv[u] = Hu[(size_t)pp[u].x * 32 + li];
        #pragma unroll
        for (int u = 0; u < 8; u++) {
            float nm = __int_as_float(pp[u].y);
            ax = fmaf(nm, bflo(gv[u]), ax);
            ay = fmaf(nm, bfhi(gv[u]), ay);
        }
    }
    for (; e < en; e++) {
        int2 p = pairs[e];
        unsigned g = Hu[(size_t)p.x * 32 + li];
        float nm = __int_as_float(p.y);
        ax = fmaf(nm, bflo(g), ax);
        ay = fmaf(nm, bfhi(g), ay);
    }
    if constexpr (BIAS) {
        float2 bb = reinterpret_cast<const float2*>(bias)[li];
        ax = d * ax + bb.x;
        ay = d * ay + bb.y;
    } else {
        ax = d * ax;
        ay = d * ay;
    }
    Out[(size_t)nd * 32 + li] = f2bf_bits(ax) | (f2bf_bits(ay) << 16);
}

// logits = sigmoid(dot(enc[a], enc[b])) — 8 lanes/pair, bf16 enc (128B rows)
__global__ void k_decode(const unsigned short* __restrict__ enc,
                         const int* __restrict__ eli, int M, float* __restrict__ out)
{
    int gid  = blockIdx.x * 256 + threadIdx.x;
    int pair = gid >> 3;
    int l    = gid & 7;
    if (pair >= M) return;
    int a = eli[pair];
    int b = eli[M + pair];
    const uint4* E4 = (const uint4*)enc;        // 8 uint4 per 64-ch row
    uint4 va = E4[(size_t)a * 8 + l];
    uint4 vb = E4[(size_t)b * 8 + l];
    float s = 0.f;
    s = fmaf(bflo(va.x), bflo(vb.x), s); s = fmaf(bfhi(va.x), bfhi(vb.x), s);
    s = fmaf(bflo(va.y), bflo(vb.y), s); s = fmaf(bfhi(va.y), bfhi(vb.y), s);
    s = fmaf(bflo(va.z), bflo(vb.z), s); s = fmaf(bfhi(va.z), bfhi(vb.z), s);
    s = fmaf(bflo(va.w), bflo(vb.w), s); s = fmaf(bfhi(va.w), bfhi(vb.w), s);
    s += __shfl_xor(s, 4, 8);
    s += __shfl_xor(s, 2, 8);
    s += __shfl_xor(s, 1, 8);
    if (l == 0) out[pair] = 1.f / (1.f + expf(-s));
}

extern "C" void kernel_launch(void* const* d_in, const int* in_sizes, int n_in,
                              void* d_out, int out_size, void* d_ws, size_t ws_size,
                              hipStream_t stream)
{
    const float* x     = (const float*)d_in[0];
    const int*   ei    = (const int*)d_in[1];
    const float* ew    = (const float*)d_in[2];
    const int*   eli   = (const int*)d_in[3];
    const float* W_in  = (const float*)d_in[4];
    const float* b_in  = (const float*)d_in[5];
    const float* W_hid = (const float*)d_in[6];
    const float* b_hid = (const float*)d_in[7];
    const float* W_out = (const float*)d_in[8];
    const float* b_out = (const float*)d_in[9];

    const int n = in_sizes[0] / 64;
    const int E = in_sizes[1] / 2;
    const int M = in_sizes[3] / 2;
    const int* row = ei;
    const int* col = ei + E;

    const int NB   = (n + 255) / 256;
    const int nb_E = (E + 255) / 256;
    const int gb   = (n + 127) / 128;
    const int ab   = (n + 3) / 4;

    // ---- workspace layout (256B-aligned regions) ----
    char* basep = (char*)d_ws;
    size_t off = 0;
    auto alloc = [&](size_t bytes) {
        char* p = basep + off; off = (off + bytes + 255) & ~(size_t)255; return p; };
    float* dinv   = (float*)alloc((size_t)n * 4);
    int*   hist   = (int*)  alloc((size_t)n * 4);
    int*   rowptr = (int*)  alloc((size_t)(n + 1) * 4);
    int*   pos    = (int*)  alloc((size_t)E * 4);
    int*   bsum   = (int*)  alloc(1024 * 4);
    int*   boff   = (int*)  alloc(1024 * 4);
    int2*  pairs  = (int2*) alloc((size_t)E * 8);
    unsigned short* wt_in  = (unsigned short*)alloc((size_t)128 * 64 * 2);
    unsigned short* wt_hid = (unsigned short*)alloc((size_t)4 * 128 * 128 * 2);
    unsigned short* wt_out = (unsigned short*)alloc((size_t)64 * 128 * 2);
    unsigned short* xb     = (unsigned short*)alloc((size_t)n * 64 * 2);   // x bf16
    unsigned short* Hbf    = (unsigned short*)alloc((size_t)n * 128 * 2);  // scratch
    unsigned short* Abf    = (unsigned short*)alloc((size_t)n * 128 * 2);  // activations
    unsigned short* enc    = (unsigned short*)alloc((size_t)n * 64 * 2);   // bf16 enc

    // ---- CSR build (atomics only in k_hist; place is atomic-free) ----
    k_zero<<<NB, 256, 0, stream>>>(hist, n);
    k_hist<<<nb_E, 256, 0, stream>>>(col, hist, pos, E);
    k_scan1<<<NB, 256, 0, stream>>>(hist, rowptr, bsum, n);
    k_scan2<<<1, 256, 0, stream>>>(bsum, boff, NB, rowptr, n);
    k_scan3<<<NB, 256, 0, stream>>>(rowptr, boff, n);
    k_place<<<nb_E, 256, 0, stream>>>(row, col, ew, rowptr, pos, pairs, E);
    k_deg<<<(n * 4 + 255) / 256, 256, 0, stream>>>(pairs, rowptr, dinv, n);
    k_premul<<<nb_E, 256, 0, stream>>>(pairs, dinv, E);

    // ---- prep: weights (one launch) + x -> bf16 ----
    k_wtall<<<320, 256, 0, stream>>>(W_in, W_hid, W_out, wt_in, wt_hid, wt_out);
    k_xbf<<<(int)(((long)n * 16 + 255) / 256), 256, 0, stream>>>(x, xb, (long)n * 16);

    // ---- layer 1 (aggregate-first): T = A_hat@x ; A1 = relu(T@W_in + b) ----
    k_aggregate64<false><<<(n + 7) / 8, 256, 0, stream>>>(
        xb, pairs, rowptr, dinv, nullptr, (unsigned*)Hbf, n);
    k_gemm_mfma<64, 128, true, true><<<gb, 256, 0, stream>>>(
        Hbf, wt_in, b_in, Abf, n);

    // ---- 4 hidden layers: 128 -> 128 ----
    for (int i = 0; i < 4; i++) {
        k_gemm_mfma<128, 128, true, false><<<gb, 256, 0, stream>>>(
            Abf, wt_hid + (size_t)i * 128 * 128, nullptr, Hbf, n);
        k_aggregate128<true><<<ab, 256, 0, stream>>>(
            Hbf, pairs, rowptr, dinv, b_hid + (size_t)i * 128, (unsigned*)Abf, n);
    }

    // ---- output layer: 128 -> 64 ----
    k_gemm_mfma<128, 64, true, false><<<gb, 256, 0, stream>>>(
        Abf, wt_out, nullptr, Hbf, n);
    k_aggregate64<true><<<(n + 7) / 8, 256, 0, stream>>>(
        Hbf, pairs, rowptr, dinv, b_out, (unsigned*)enc, n);

    // ---- decoder ----
    k_decode<<<(M * 8 + 255) / 256, 256, 0, stream>>>(enc, eli, M, (float*)d_out);
}

// Round 14
// 614.648 us; speedup vs baseline: 1.1811x; 1.0056x over previous
//
#include <hip/hip_runtime.h>
#include <hip/hip_bf16.h>
#include <math.h>

// ---------------------------------------------------------------------------
// GCN link-prediction encoder: 6 GCN layers + dot-product decoder.
// R14 = R13 with gather burst depth tuned to the degree distribution
// (mean deg = 16): agg128 12 -> 16, agg64 8 -> 12. All else frozen.
// ---------------------------------------------------------------------------

using bf16x8 = __attribute__((ext_vector_type(8))) short;  // 8 bf16 = 4 VGPRs
using f32x4  = __attribute__((ext_vector_type(4))) float;

__device__ inline unsigned f2bf_bits(float f) {            // RNE f32 -> bf16
    unsigned u = __float_as_uint(f);
    return (u + 0x7fffu + ((u >> 16) & 1u)) >> 16;
}
__device__ inline float bflo(unsigned w) { return __uint_as_float(w << 16); }
__device__ inline float bfhi(unsigned w) { return __uint_as_float(w & 0xffff0000u); }

// ---------------- CSR build (int-only atomics) ----------------

__global__ void k_zero(int* __restrict__ hist, int n) {
    int i = blockIdx.x * 256 + threadIdx.x;
    if (i < n) hist[i] = 0;
}

// histogram + per-edge slot reservation (fetch-add return)
__global__ void k_hist(const int* __restrict__ col, int* __restrict__ hist,
                       int* __restrict__ pos, int E) {
    int i = blockIdx.x * 256 + threadIdx.x;
    if (i < E) pos[i] = atomicAdd(&hist[col[i]], 1);
}

__global__ __launch_bounds__(256) void k_scan1(const int* __restrict__ hist,
                                               int* __restrict__ rowptr,
                                               int* __restrict__ bsum, int n) {
    __shared__ int lds[256];
    int t = threadIdx.x;
    int idx = blockIdx.x * 256 + t;
    int v = (idx < n) ? hist[idx] : 0;
    lds[t] = v; __syncthreads();
    for (int off = 1; off < 256; off <<= 1) {
        int x = (t >= off) ? lds[t - off] : 0;
        __syncthreads();
        lds[t] += x;
        __syncthreads();
    }
    if (idx < n) rowptr[idx] = lds[t] - v;
    if (t == 255) bsum[blockIdx.x] = lds[255];
}

__global__ __launch_bounds__(256) void k_scan2(const int* __restrict__ bsum,
                                               int* __restrict__ boff, int nb,
                                               int* __restrict__ rowptr, int n) {
    __shared__ int lds[256];
    int t = threadIdx.x;
    int carry = 0;
    for (int base = 0; base < nb; base += 256) {
        int v = (base + t < nb) ? bsum[base + t] : 0;
        lds[t] = v; __syncthreads();
        for (int off = 1; off < 256; off <<= 1) {
            int x = (t >= off) ? lds[t - off] : 0;
            __syncthreads();
            lds[t] += x;
            __syncthreads();
        }
        if (base + t < nb) boff[base + t] = carry + lds[t] - v;
        carry += lds[255];
        __syncthreads();
    }
    if (t == 0) rowptr[n] = carry;
}

__global__ void k_scan3(int* __restrict__ rowptr, const int* __restrict__ boff, int n) {
    int i = blockIdx.x * 256 + threadIdx.x;
    if (i < n) rowptr[i] += boff[blockIdx.x];
}

// place edges col-sorted, storing {row, ew} — NO atomics (slot precomputed)
__global__ void k_place(const int* __restrict__ row, const int* __restrict__ col,
                        const float* __restrict__ ew, const int* __restrict__ rowptr,
                        const int* __restrict__ pos, int2* __restrict__ pairs, int E) {
    int e = blockIdx.x * 256 + threadIdx.x;
    if (e >= E) return;
    int c = col[e];
    int slot = rowptr[c] + pos[e];
    pairs[slot] = make_int2(row[e], __float_as_int(ew[e]));
}

// dinv[g] = rsqrt(1 + sum ew over g's segment) — 4 lanes per node
__global__ void k_deg(const int2* __restrict__ pairs, const int* __restrict__ rowptr,
                      float* __restrict__ dinv, int n) {
    int t = blockIdx.x * 256 + threadIdx.x;
    int g = t >> 2, sub = t & 3;
    if (g >= n) return;
    int s = rowptr[g], e = rowptr[g + 1];
    float acc = 0.f;
    for (int i = s + sub; i < e; i += 4) acc += __int_as_float(pairs[i].y);
    acc += __shfl_xor(acc, 1, 4);
    acc += __shfl_xor(acc, 2, 4);
    if (sub == 0) dinv[g] = rsqrtf(1.f + acc);
}

// pairs.y: ew -> dinv[row]*ew (dest-side d applied in aggregate epilogue)
__global__ void k_premul(int2* __restrict__ pairs, const float* __restrict__ dinv, int E) {
    int e = blockIdx.x * 256 + threadIdx.x;
    if (e >= E) return;
    int2 p = pairs[e];
    pairs[e] = make_int2(p.x, __float_as_int(dinv[p.x] * __int_as_float(p.y)));
}

// x f32 -> bf16 (4 per thread)
__global__ void k_xbf(const float* __restrict__ x, unsigned short* __restrict__ xb,
                      long total4) {
    long i = (long)blockIdx.x * 256 + threadIdx.x;
    if (i >= total4) return;
    float4 v = reinterpret_cast<const float4*>(x)[i];
    ushort4 o;
    o.x = (unsigned short)f2bf_bits(v.x);
    o.y = (unsigned short)f2bf_bits(v.y);
    o.z = (unsigned short)f2bf_bits(v.z);
    o.w = (unsigned short)f2bf_bits(v.w);
    reinterpret_cast<ushort4*>(xb)[i] = o;
}

// ---------------- weight prep: all weights, one launch ----------------
__global__ void k_wtall(const float* __restrict__ W_in, const float* __restrict__ W_hid,
                        const float* __restrict__ W_out,
                        unsigned short* __restrict__ wt_in,
                        unsigned short* __restrict__ wt_hid,
                        unsigned short* __restrict__ wt_out) {
    int i = blockIdx.x * 256 + threadIdx.x;
    if (i < 8192) {                       // W_in: K=64, N=128
        int k = i / 128, nn = i % 128;
        wt_in[nn * 64 + k] = (unsigned short)f2bf_bits(W_in[i]);
    } else if (i < 73728) {               // W_hid: 4 x (K=128, N=128)
        int j = i - 8192;
        int l = j >> 14, r = j & 16383;
        int k = r / 128, nn = r % 128;
        wt_hid[l * 16384 + nn * 128 + k] = (unsigned short)f2bf_bits(W_hid[j]);
    } else if (i < 81920) {               // W_out: K=128, N=64
        int j = i - 73728;
        int k = j / 64, nn = j % 64;
        wt_out[nn * 128 + k] = (unsigned short)f2bf_bits(W_out[j]);
    }
}

// ---------------- MFMA GEMM: H = X @ W (+bias, relu if EPI) ---------------
// 128-row tile, 256 threads = 4 waves. LDS XOR-swizzled (byte ^= (row&7)<<4).
template <int K, int N, bool IN_BF16, bool EPI>
__global__ __launch_bounds__(256, 2) void k_gemm_mfma(
    const void* __restrict__ Xv, const unsigned short* __restrict__ Wt,
    const float* __restrict__ bias, unsigned short* __restrict__ H, int n)
{
    constexpr int NREP = N / 16;
    constexpr int KC   = K / 8;          // 16B chunks per row
    __shared__ char lds[128 * K * 2 + N * K * 2];
    char* Xs = lds;
    char* Ws = lds + 128 * K * 2;

    const int row0 = blockIdx.x * 128;
    const int tid  = threadIdx.x;

    for (int c = tid; c < 128 * KC; c += 256) {
        int r = c / KC, kc = c % KC;
        int gr = row0 + r;
        bf16x8 v = {0, 0, 0, 0, 0, 0, 0, 0};
        if (gr < n) {
            if constexpr (IN_BF16) {
                v = *(const bf16x8*)((const unsigned short*)Xv + (size_t)gr * K + kc * 8);
            } else {
                const float* xp = (const float*)Xv + (size_t)gr * K + kc * 8;
                float4 a = *(const float4*)xp;
                float4 b = *(const float4*)(xp + 4);
                v[0] = (short)f2bf_bits(a.x); v[1] = (short)f2bf_bits(a.y);
                v[2] = (short)f2bf_bits(a.z); v[3] = (short)f2bf_bits(a.w);
                v[4] = (short)f2bf_bits(b.x); v[5] = (short)f2bf_bits(b.y);
                v[6] = (short)f2bf_bits(b.z); v[7] = (short)f2bf_bits(b.w);
            }
        }
        *(bf16x8*)(Xs + ((r * (K * 2) + kc * 16) ^ ((r & 7) << 4))) = v;
    }
    for (int c = tid; c < N * KC; c += 256) {
        int r = c / KC, kc = c % KC;
        bf16x8 v = *(const bf16x8*)(Wt + (size_t)r * K + kc * 8);
        *(bf16x8*)(Ws + ((r * (K * 2) + kc * 16) ^ ((r & 7) << 4))) = v;
    }
    __syncthreads();

    const int wv   = tid >> 6;
    const int lane = tid & 63;
    const int lr   = lane & 15;
    const int lk   = lane >> 4;

    f32x4 acc[2][NREP];
    #pragma unroll
    for (int m = 0; m < 2; m++)
        #pragma unroll
        for (int j = 0; j < NREP; j++)
            acc[m][j] = (f32x4){0.f, 0.f, 0.f, 0.f};

    #pragma unroll
    for (int kk = 0; kk < K / 32; kk++) {
        int kc = kk * 4 + lk;
        bf16x8 af[2];
        #pragma unroll
        for (int m = 0; m < 2; m++) {
            int r = wv * 32 + m * 16 + lr;
            af[m] = *(const bf16x8*)(Xs + ((r * (K * 2) + kc * 16) ^ ((r & 7) << 4)));
        }
        #pragma unroll
        for (int j = 0; j < NREP; j++) {
            int r = j * 16 + lr;
            bf16x8 bfr = *(const bf16x8*)(Ws + ((r * (K * 2) + kc * 16) ^ ((r & 7) << 4)));
            acc[0][j] = __builtin_amdgcn_mfma_f32_16x16x32_bf16(af[0], bfr, acc[0][j], 0, 0, 0);
            acc[1][j] = __builtin_amdgcn_mfma_f32_16x16x32_bf16(af[1], bfr, acc[1][j], 0, 0, 0);
        }
    }

    #pragma unroll
    for (int m = 0; m < 2; m++) {
        #pragma unroll
        for (int j = 0; j < NREP; j++) {
            float bcol = EPI ? bias[j * 16 + lr] : 0.f;
            #pragma unroll
            for (int rr = 0; rr < 4; rr++) {
                int gr = row0 + wv * 32 + m * 16 + lk * 4 + rr;
                if (gr < n) {
                    float v = acc[m][j][rr];
                    if constexpr (EPI) v = fmaxf(v + bcol, 0.f);
                    H[(size_t)gr * N + j * 16 + lr] = (unsigned short)f2bf_bits(v);
                }
            }
        }
    }
}

// ---------------- gather-aggregate (128ch): premul pairs, 16-deep ---------
// Out[c] = act( d*( d*H[c] + sum_e p.y*H[row[e]] ) + b )
template <bool RELU>
__global__ __launch_bounds__(256) void k_aggregate128(
    const unsigned short* __restrict__ H, const int2* __restrict__ pairs,
    const int* __restrict__ rowptr, const float* __restrict__ dinv,
    const float* __restrict__ bias, unsigned* __restrict__ Out, int n)
{
    const int lane = threadIdx.x & 63;
    const int w    = threadIdx.x >> 6;
    int nd = blockIdx.x * 4 + w;
    if (nd >= n) return;
    int s  = rowptr[nd];
    int en = rowptr[nd + 1];
    float d = dinv[nd];

    const unsigned* Hu = (const unsigned*)H;
    unsigned sw = Hu[(size_t)nd * 64 + lane];
    float ax = d * bflo(sw), ay = d * bfhi(sw);
    int e = s;
    for (; e + 16 <= en; e += 16) {             // 16-deep burst (mean deg = 16)
        int2 pp[16]; unsigned gv[16];
        #pragma unroll
        for (int u = 0; u < 16; u++) pp[u] = pairs[e + u];
        #pragma unroll
        for (int u = 0; u < 16; u++) gv[u] = Hu[(size_t)pp[u].x * 64 + lane];
        #pragma unroll
        for (int u = 0; u < 16; u++) {
            float nm = __int_as_float(pp[u].y);
            ax = fmaf(nm, bflo(gv[u]), ax);
            ay = fmaf(nm, bfhi(gv[u]), ay);
        }
    }
    for (; e + 4 <= en; e += 4) {
        int2 pp[4]; unsigned gv[4];
        #pragma unroll
        for (int u = 0; u < 4; u++) pp[u] = pairs[e + u];
        #pragma unroll
        for (int u = 0; u < 4; u++) gv[u] = Hu[(size_t)pp[u].x * 64 + lane];
        #pragma unroll
        for (int u = 0; u < 4; u++) {
            float nm = __int_as_float(pp[u].y);
            ax = fmaf(nm, bflo(gv[u]), ax);
            ay = fmaf(nm, bfhi(gv[u]), ay);
        }
    }
    for (; e < en; e++) {
        int2 p = pairs[e];
        unsigned g = Hu[(size_t)p.x * 64 + lane];
        float nm = __int_as_float(p.y);
        ax = fmaf(nm, bflo(g), ax);
        ay = fmaf(nm, bfhi(g), ay);
    }
    float2 bb = reinterpret_cast<const float2*>(bias)[lane];
    ax = d * ax + bb.x;
    ay = d * ay + bb.y;
    if (RELU) { ax = fmaxf(ax, 0.f); ay = fmaxf(ay, 0.f); }
    Out[(size_t)nd * 64 + lane] = f2bf_bits(ax) | (f2bf_bits(ay) << 16);
}

// ---------------- gather-aggregate (64ch): 2 nodes/wave, 12-deep ----------
// BIAS=false: pure T = A_hat@X (layer-1 input aggregation).
// BIAS=true : output layer (bias, no relu).
template <bool BIAS>
__global__ __launch_bounds__(256) void k_aggregate64(
    const unsigned short* __restrict__ H, const int2* __restrict__ pairs,
    const int* __restrict__ rowptr, const float* __restrict__ dinv,
    const float* __restrict__ bias, unsigned* __restrict__ Out, int n)
{
    const int lane = threadIdx.x & 63;
    const int w    = threadIdx.x >> 6;
    const int li   = lane & 31;                 // uint index within row
    int nd = (blockIdx.x * 4 + w) * 2 + (lane >> 5);
    if (nd >= n) return;
    int s  = rowptr[nd];
    int en = rowptr[nd + 1];
    float d = dinv[nd];

    const unsigned* Hu = (const unsigned*)H;    // 32 uints per row
    unsigned sw = Hu[(size_t)nd * 32 + li];
    float ax = d * bflo(sw), ay = d * bfhi(sw);
    int e = s;
    for (; e + 12 <= en; e += 12) {
        int2 pp[12]; unsigned gv[12];
        #pragma unroll
        for (int u = 0; u < 12; u++) pp[u] = pairs[e + u];
        #pragma unroll
        for (int u = 0; u < 12; u++) gv[u] = Hu[(size_t)pp[u].x * 32 + li];
        #pragma unroll
        for (int u = 0; u < 12; u++) {
            float nm = __int_as_float(pp[u].y);
            ax = fmaf(nm, bflo(gv[u]), ax);
            ay = fmaf(nm, bfhi(gv[u]), ay);
        }
    }
    for (; e + 4 <= en; e += 4) {
        int2 pp[4]; unsigned gv[4];
        #pragma unroll
        for (int u = 0; u < 4; u++) pp[u] = pairs[e + u];
        #pragma unroll
        for (int u = 0; u < 4; u++) gv[u] = Hu[(size_t)pp[u].x * 32 + li];
        #pragma unroll
        for (int u = 0; u < 4; u++) {
            float nm = __int_as_float(pp[u].y);
            ax = fmaf(nm, bflo(gv[u]), ax);
            ay = fmaf(nm, bfhi(gv[u]), ay);
        }
    }
    for (; e < en; e++) {
        int2 p = pairs[e];
        unsigned g = Hu[(size_t)p.x * 32 + li];
        float nm = __int_as_float(p.y);
        ax = fmaf(nm, bflo(g), ax);
        ay = fmaf(nm, bfhi(g), ay);
    }
    if constexpr (BIAS) {
        float2 bb = reinterpret_cast<const float2*>(bias)[li];
        ax = d * ax + bb.x;
        ay = d * ay + bb.y;
    } else {
        ax = d * ax;
        ay = d * ay;
    }
    Out[(size_t)nd * 32 + li] = f2bf_bits(ax) | (f2bf_bits(ay) << 16);
}

// logits = sigmoid(dot(enc[a], enc[b])) — 8 lanes/pair, bf16 enc (128B rows)
__global__ void k_decode(const unsigned short* __restrict__ enc,
                         const int* __restrict__ eli, int M, float* __restrict__ out)
{
    int gid  = blockIdx.x * 256 + threadIdx.x;
    int pair = gid >> 3;
    int l    = gid & 7;
    if (pair >= M) return;
    int a = eli[pair];
    int b = eli[M + pair];
    const uint4* E4 = (const uint4*)enc;        // 8 uint4 per 64-ch row
    uint4 va = E4[(size_t)a * 8 + l];
    uint4 vb = E4[(size_t)b * 8 + l];
    float s = 0.f;
    s = fmaf(bflo(va.x), bflo(vb.x), s); s = fmaf(bfhi(va.x), bfhi(vb.x), s);
    s = fmaf(bflo(va.y), bflo(vb.y), s); s = fmaf(bfhi(va.y), bfhi(vb.y), s);
    s = fmaf(bflo(va.z), bflo(vb.z), s); s = fmaf(bfhi(va.z), bfhi(vb.z), s);
    s = fmaf(bflo(va.w), bflo(vb.w), s); s = fmaf(bfhi(va.w), bfhi(vb.w), s);
    s += __shfl_xor(s, 4, 8);
    s += __shfl_xor(s, 2, 8);
    s += __shfl_xor(s, 1, 8);
    if (l == 0) out[pair] = 1.f / (1.f + expf(-s));
}

extern "C" void kernel_launch(void* const* d_in, const int* in_sizes, int n_in,
                              void* d_out, int out_size, void* d_ws, size_t ws_size,
                              hipStream_t stream)
{
    const float* x     = (const float*)d_in[0];
    const int*   ei    = (const int*)d_in[1];
    const float* ew    = (const float*)d_in[2];
    const int*   eli   = (const int*)d_in[3];
    const float* W_in  = (const float*)d_in[4];
    const float* b_in  = (const float*)d_in[5];
    const float* W_hid = (const float*)d_in[6];
    const float* b_hid = (const float*)d_in[7];
    const float* W_out = (const float*)d_in[8];
    const float* b_out = (const float*)d_in[9];

    const int n = in_sizes[0] / 64;
    const int E = in_sizes[1] / 2;
    const int M = in_sizes[3] / 2;
    const int* row = ei;
    const int* col = ei + E;

    const int NB   = (n + 255) / 256;
    const int nb_E = (E + 255) / 256;
    const int gb   = (n + 127) / 128;
    const int ab   = (n + 3) / 4;

    // ---- workspace layout (256B-aligned regions) ----
    char* basep = (char*)d_ws;
    size_t off = 0;
    auto alloc = [&](size_t bytes) {
        char* p = basep + off; off = (off + bytes + 255) & ~(size_t)255; return p; };
    float* dinv   = (float*)alloc((size_t)n * 4);
    int*   hist   = (int*)  alloc((size_t)n * 4);
    int*   rowptr = (int*)  alloc((size_t)(n + 1) * 4);
    int*   pos    = (int*)  alloc((size_t)E * 4);
    int*   bsum   = (int*)  alloc(1024 * 4);
    int*   boff   = (int*)  alloc(1024 * 4);
    int2*  pairs  = (int2*) alloc((size_t)E * 8);
    unsigned short* wt_in  = (unsigned short*)alloc((size_t)128 * 64 * 2);
    unsigned short* wt_hid = (unsigned short*)alloc((size_t)4 * 128 * 128 * 2);
    unsigned short* wt_out = (unsigned short*)alloc((size_t)64 * 128 * 2);
    unsigned short* xb     = (unsigned short*)alloc((size_t)n * 64 * 2);   // x bf16
    unsigned short* Hbf    = (unsigned short*)alloc((size_t)n * 128 * 2);  // scratch
    unsigned short* Abf    = (unsigned short*)alloc((size_t)n * 128 * 2);  // activations
    unsigned short* enc    = (unsigned short*)alloc((size_t)n * 64 * 2);   // bf16 enc

    // ---- CSR build (atomics only in k_hist; place is atomic-free) ----
    k_zero<<<NB, 256, 0, stream>>>(hist, n);
    k_hist<<<nb_E, 256, 0, stream>>>(col, hist, pos, E);
    k_scan1<<<NB, 256, 0, stream>>>(hist, rowptr, bsum, n);
    k_scan2<<<1, 256, 0, stream>>>(bsum, boff, NB, rowptr, n);
    k_scan3<<<NB, 256, 0, stream>>>(rowptr, boff, n);
    k_place<<<nb_E, 256, 0, stream>>>(row, col, ew, rowptr, pos, pairs, E);
    k_deg<<<(n * 4 + 255) / 256, 256, 0, stream>>>(pairs, rowptr, dinv, n);
    k_premul<<<nb_E, 256, 0, stream>>>(pairs, dinv, E);

    // ---- prep: weights (one launch) + x -> bf16 ----
    k_wtall<<<320, 256, 0, stream>>>(W_in, W_hid, W_out, wt_in, wt_hid, wt_out);
    k_xbf<<<(int)(((long)n * 16 + 255) / 256), 256, 0, stream>>>(x, xb, (long)n * 16);

    // ---- layer 1 (aggregate-first): T = A_hat@x ; A1 = relu(T@W_in + b) ----
    k_aggregate64<false><<<(n + 7) / 8, 256, 0, stream>>>(
        xb, pairs, rowptr, dinv, nullptr, (unsigned*)Hbf, n);
    k_gemm_mfma<64, 128, true, true><<<gb, 256, 0, stream>>>(
        Hbf, wt_in, b_in, Abf, n);

    // ---- 4 hidden layers: 128 -> 128 ----
    for (int i = 0; i < 4; i++) {
        k_gemm_mfma<128, 128, true, false><<<gb, 256, 0, stream>>>(
            Abf, wt_hid + (size_t)i * 128 * 128, nullptr, Hbf, n);
        k_aggregate128<true><<<ab, 256, 0, stream>>>(
            Hbf, pairs, rowptr, dinv, b_hid + (size_t)i * 128, (unsigned*)Abf, n);
    }

    // ---- output layer: 128 -> 64 ----
    k_gemm_mfma<128, 64, true, false><<<gb, 256, 0, stream>>>(
        Abf, wt_out, nullptr, Hbf, n);
    k_aggregate64<true><<<(n + 7) / 8, 256, 0, stream>>>(
        Hbf, pairs, rowptr, dinv, b_out, (unsigned*)enc, n);

    // ---- decoder ----
    k_decode<<<(M * 8 + 255) / 256, 256, 0, stream>>>(enc, eli, M, (float*)d_out);
}

// Round 15
// 607.195 us; speedup vs baseline: 1.1956x; 1.0123x over previous
//
#include <hip/hip_runtime.h>
#include <hip/hip_bf16.h>
#include <math.h>

// ---------------------------------------------------------------------------
// GCN link-prediction encoder: 6 GCN layers + dot-product decoder.
// R15: agg128 reverted to measured-best 12-deep burst (16 was past the peak);
// agg64 stays 12-deep; k_wtall+k_xbf merged into one k_prep launch.
// ---------------------------------------------------------------------------

using bf16x8 = __attribute__((ext_vector_type(8))) short;  // 8 bf16 = 4 VGPRs
using f32x4  = __attribute__((ext_vector_type(4))) float;

__device__ inline unsigned f2bf_bits(float f) {            // RNE f32 -> bf16
    unsigned u = __float_as_uint(f);
    return (u + 0x7fffu + ((u >> 16) & 1u)) >> 16;
}
__device__ inline float bflo(unsigned w) { return __uint_as_float(w << 16); }
__device__ inline float bfhi(unsigned w) { return __uint_as_float(w & 0xffff0000u); }

// ---------------- CSR build (int-only atomics) ----------------

__global__ void k_zero(int* __restrict__ hist, int n) {
    int i = blockIdx.x * 256 + threadIdx.x;
    if (i < n) hist[i] = 0;
}

// histogram + per-edge slot reservation (fetch-add return)
__global__ void k_hist(const int* __restrict__ col, int* __restrict__ hist,
                       int* __restrict__ pos, int E) {
    int i = blockIdx.x * 256 + threadIdx.x;
    if (i < E) pos[i] = atomicAdd(&hist[col[i]], 1);
}

__global__ __launch_bounds__(256) void k_scan1(const int* __restrict__ hist,
                                               int* __restrict__ rowptr,
                                               int* __restrict__ bsum, int n) {
    __shared__ int lds[256];
    int t = threadIdx.x;
    int idx = blockIdx.x * 256 + t;
    int v = (idx < n) ? hist[idx] : 0;
    lds[t] = v; __syncthreads();
    for (int off = 1; off < 256; off <<= 1) {
        int x = (t >= off) ? lds[t - off] : 0;
        __syncthreads();
        lds[t] += x;
        __syncthreads();
    }
    if (idx < n) rowptr[idx] = lds[t] - v;
    if (t == 255) bsum[blockIdx.x] = lds[255];
}

__global__ __launch_bounds__(256) void k_scan2(const int* __restrict__ bsum,
                                               int* __restrict__ boff, int nb,
                                               int* __restrict__ rowptr, int n) {
    __shared__ int lds[256];
    int t = threadIdx.x;
    int carry = 0;
    for (int base = 0; base < nb; base += 256) {
        int v = (base + t < nb) ? bsum[base + t] : 0;
        lds[t] = v; __syncthreads();
        for (int off = 1; off < 256; off <<= 1) {
            int x = (t >= off) ? lds[t - off] : 0;
            __syncthreads();
            lds[t] += x;
            __syncthreads();
        }
        if (base + t < nb) boff[base + t] = carry + lds[t] - v;
        carry += lds[255];
        __syncthreads();
    }
    if (t == 0) rowptr[n] = carry;
}

__global__ void k_scan3(int* __restrict__ rowptr, const int* __restrict__ boff, int n) {
    int i = blockIdx.x * 256 + threadIdx.x;
    if (i < n) rowptr[i] += boff[blockIdx.x];
}

// place edges col-sorted, storing {row, ew} — NO atomics (slot precomputed)
__global__ void k_place(const int* __restrict__ row, const int* __restrict__ col,
                        const float* __restrict__ ew, const int* __restrict__ rowptr,
                        const int* __restrict__ pos, int2* __restrict__ pairs, int E) {
    int e = blockIdx.x * 256 + threadIdx.x;
    if (e >= E) return;
    int c = col[e];
    int slot = rowptr[c] + pos[e];
    pairs[slot] = make_int2(row[e], __float_as_int(ew[e]));
}

// dinv[g] = rsqrt(1 + sum ew over g's segment) — 4 lanes per node
__global__ void k_deg(const int2* __restrict__ pairs, const int* __restrict__ rowptr,
                      float* __restrict__ dinv, int n) {
    int t = blockIdx.x * 256 + threadIdx.x;
    int g = t >> 2, sub = t & 3;
    if (g >= n) return;
    int s = rowptr[g], e = rowptr[g + 1];
    float acc = 0.f;
    for (int i = s + sub; i < e; i += 4) acc += __int_as_float(pairs[i].y);
    acc += __shfl_xor(acc, 1, 4);
    acc += __shfl_xor(acc, 2, 4);
    if (sub == 0) dinv[g] = rsqrtf(1.f + acc);
}

// pairs.y: ew -> dinv[row]*ew (dest-side d applied in aggregate epilogue)
__global__ void k_premul(int2* __restrict__ pairs, const float* __restrict__ dinv, int E) {
    int e = blockIdx.x * 256 + threadIdx.x;
    if (e >= E) return;
    int2 p = pairs[e];
    pairs[e] = make_int2(p.x, __float_as_int(dinv[p.x] * __int_as_float(p.y)));
}

// ---------------- prep: x -> bf16 AND all weight transposes, one launch ----
// thread i < X4: convert x float4 #i. else j = i - X4 indexes weights.
__global__ void k_prep(const float* __restrict__ x, unsigned short* __restrict__ xb,
                       long X4,
                       const float* __restrict__ W_in, const float* __restrict__ W_hid,
                       const float* __restrict__ W_out,
                       unsigned short* __restrict__ wt_in,
                       unsigned short* __restrict__ wt_hid,
                       unsigned short* __restrict__ wt_out) {
    long i = (long)blockIdx.x * 256 + threadIdx.x;
    if (i < X4) {
        float4 v = reinterpret_cast<const float4*>(x)[i];
        ushort4 o;
        o.x = (unsigned short)f2bf_bits(v.x);
        o.y = (unsigned short)f2bf_bits(v.y);
        o.z = (unsigned short)f2bf_bits(v.z);
        o.w = (unsigned short)f2bf_bits(v.w);
        reinterpret_cast<ushort4*>(xb)[i] = o;
        return;
    }
    int j = (int)(i - X4);
    if (j < 8192) {                       // W_in: K=64, N=128
        int k = j / 128, nn = j % 128;
        wt_in[nn * 64 + k] = (unsigned short)f2bf_bits(W_in[j]);
    } else if (j < 73728) {               // W_hid: 4 x (K=128, N=128)
        int r0 = j - 8192;
        int l = r0 >> 14, r = r0 & 16383;
        int k = r / 128, nn = r % 128;
        wt_hid[l * 16384 + nn * 128 + k] = (unsigned short)f2bf_bits(W_hid[r0]);
    } else if (j < 81920) {               // W_out: K=128, N=64
        int r0 = j - 73728;
        int k = r0 / 64, nn = r0 % 64;
        wt_out[nn * 128 + k] = (unsigned short)f2bf_bits(W_out[r0]);
    }
}

// ---------------- MFMA GEMM: H = X @ W (+bias, relu if EPI) ---------------
// 128-row tile, 256 threads = 4 waves. LDS XOR-swizzled (byte ^= (row&7)<<4).
template <int K, int N, bool IN_BF16, bool EPI>
__global__ __launch_bounds__(256, 2) void k_gemm_mfma(
    const void* __restrict__ Xv, const unsigned short* __restrict__ Wt,
    const float* __restrict__ bias, unsigned short* __restrict__ H, int n)
{
    constexpr int NREP = N / 16;
    constexpr int KC   = K / 8;          // 16B chunks per row
    __shared__ char lds[128 * K * 2 + N * K * 2];
    char* Xs = lds;
    char* Ws = lds + 128 * K * 2;

    const int row0 = blockIdx.x * 128;
    const int tid  = threadIdx.x;

    for (int c = tid; c < 128 * KC; c += 256) {
        int r = c / KC, kc = c % KC;
        int gr = row0 + r;
        bf16x8 v = {0, 0, 0, 0, 0, 0, 0, 0};
        if (gr < n) {
            if constexpr (IN_BF16) {
                v = *(const bf16x8*)((const unsigned short*)Xv + (size_t)gr * K + kc * 8);
            } else {
                const float* xp = (const float*)Xv + (size_t)gr * K + kc * 8;
                float4 a = *(const float4*)xp;
                float4 b = *(const float4*)(xp + 4);
                v[0] = (short)f2bf_bits(a.x); v[1] = (short)f2bf_bits(a.y);
                v[2] = (short)f2bf_bits(a.z); v[3] = (short)f2bf_bits(a.w);
                v[4] = (short)f2bf_bits(b.x); v[5] = (short)f2bf_bits(b.y);
                v[6] = (short)f2bf_bits(b.z); v[7] = (short)f2bf_bits(b.w);
            }
        }
        *(bf16x8*)(Xs + ((r * (K * 2) + kc * 16) ^ ((r & 7) << 4))) = v;
    }
    for (int c = tid; c < N * KC; c += 256) {
        int r = c / KC, kc = c % KC;
        bf16x8 v = *(const bf16x8*)(Wt + (size_t)r * K + kc * 8);
        *(bf16x8*)(Ws + ((r * (K * 2) + kc * 16) ^ ((r & 7) << 4))) = v;
    }
    __syncthreads();

    const int wv   = tid >> 6;
    const int lane = tid & 63;
    const int lr   = lane & 15;
    const int lk   = lane >> 4;

    f32x4 acc[2][NREP];
    #pragma unroll
    for (int m = 0; m < 2; m++)
        #pragma unroll
        for (int j = 0; j < NREP; j++)
            acc[m][j] = (f32x4){0.f, 0.f, 0.f, 0.f};

    #pragma unroll
    for (int kk = 0; kk < K / 32; kk++) {
        int kc = kk * 4 + lk;
        bf16x8 af[2];
        #pragma unroll
        for (int m = 0; m < 2; m++) {
            int r = wv * 32 + m * 16 + lr;
            af[m] = *(const bf16x8*)(Xs + ((r * (K * 2) + kc * 16) ^ ((r & 7) << 4)));
        }
        #pragma unroll
        for (int j = 0; j < NREP; j++) {
            int r = j * 16 + lr;
            bf16x8 bfr = *(const bf16x8*)(Ws + ((r * (K * 2) + kc * 16) ^ ((r & 7) << 4)));
            acc[0][j] = __builtin_amdgcn_mfma_f32_16x16x32_bf16(af[0], bfr, acc[0][j], 0, 0, 0);
            acc[1][j] = __builtin_amdgcn_mfma_f32_16x16x32_bf16(af[1], bfr, acc[1][j], 0, 0, 0);
        }
    }

    #pragma unroll
    for (int m = 0; m < 2; m++) {
        #pragma unroll
        for (int j = 0; j < NREP; j++) {
            float bcol = EPI ? bias[j * 16 + lr] : 0.f;
            #pragma unroll
            for (int rr = 0; rr < 4; rr++) {
                int gr = row0 + wv * 32 + m * 16 + lk * 4 + rr;
                if (gr < n) {
                    float v = acc[m][j][rr];
                    if constexpr (EPI) v = fmaxf(v + bcol, 0.f);
                    H[(size_t)gr * N + j * 16 + lr] = (unsigned short)f2bf_bits(v);
                }
            }
        }
    }
}

// ---------------- gather-aggregate (128ch): premul pairs, 12-deep ---------
// Out[c] = act( d*( d*H[c] + sum_e p.y*H[row[e]] ) + b )
template <bool RELU>
__global__ __launch_bounds__(256) void k_aggregate128(
    const unsigned short* __restrict__ H, const int2* __restrict__ pairs,
    const int* __restrict__ rowptr, const float* __restrict__ dinv,
    const float* __restrict__ bias, unsigned* __restrict__ Out, int n)
{
    const int lane = threadIdx.x & 63;
    const int w    = threadIdx.x >> 6;
    int nd = blockIdx.x * 4 + w;
    if (nd >= n) return;
    int s  = rowptr[nd];
    int en = rowptr[nd + 1];
    float d = dinv[nd];

    const unsigned* Hu = (const unsigned*)H;
    unsigned sw = Hu[(size_t)nd * 64 + lane];
    float ax = d * bflo(sw), ay = d * bfhi(sw);
    int e = s;
    for (; e + 12 <= en; e += 12) {             // 12-deep (measured optimum)
        int2 pp[12]; unsigned gv[12];
        #pragma unroll
        for (int u = 0; u < 12; u++) pp[u] = pairs[e + u];
        #pragma unroll
        for (int u = 0; u < 12; u++) gv[u] = Hu[(size_t)pp[u].x * 64 + lane];
        #pragma unroll
        for (int u = 0; u < 12; u++) {
            float nm = __int_as_float(pp[u].y);
            ax = fmaf(nm, bflo(gv[u]), ax);
            ay = fmaf(nm, bfhi(gv[u]), ay);
        }
    }
    for (; e + 4 <= en; e += 4) {
        int2 pp[4]; unsigned gv[4];
        #pragma unroll
        for (int u = 0; u < 4; u++) pp[u] = pairs[e + u];
        #pragma unroll
        for (int u = 0; u < 4; u++) gv[u] = Hu[(size_t)pp[u].x * 64 + lane];
        #pragma unroll
        for (int u = 0; u < 4; u++) {
            float nm = __int_as_float(pp[u].y);
            ax = fmaf(nm, bflo(gv[u]), ax);
            ay = fmaf(nm, bfhi(gv[u]), ay);
        }
    }
    for (; e < en; e++) {
        int2 p = pairs[e];
        unsigned g = Hu[(size_t)p.x * 64 + lane];
        float nm = __int_as_float(p.y);
        ax = fmaf(nm, bflo(g), ax);
        ay = fmaf(nm, bfhi(g), ay);
    }
    float2 bb = reinterpret_cast<const float2*>(bias)[lane];
    ax = d * ax + bb.x;
    ay = d * ay + bb.y;
    if (RELU) { ax = fmaxf(ax, 0.f); ay = fmaxf(ay, 0.f); }
    Out[(size_t)nd * 64 + lane] = f2bf_bits(ax) | (f2bf_bits(ay) << 16);
}

// ---------------- gather-aggregate (64ch): 2 nodes/wave, 12-deep ----------
// BIAS=false: pure T = A_hat@X (layer-1 input aggregation).
// BIAS=true : output layer (bias, no relu).
template <bool BIAS>
__global__ __launch_bounds__(256) void k_aggregate64(
    const unsigned short* __restrict__ H, const int2* __restrict__ pairs,
    const int* __restrict__ rowptr, const float* __restrict__ dinv,
    const float* __restrict__ bias, unsigned* __restrict__ Out, int n)
{
    const int lane = threadIdx.x & 63;
    const int w    = threadIdx.x >> 6;
    const int li   = lane & 31;                 // uint index within row
    int nd = (blockIdx.x * 4 + w) * 2 + (lane >> 5);
    if (nd >= n) return;
    int s  = rowptr[nd];
    int en = rowptr[nd + 1];
    float d = dinv[nd];

    const unsigned* Hu = (const unsigned*)H;    // 32 uints per row
    unsigned sw = Hu[(size_t)nd * 32 + li];
    float ax = d * bflo(sw), ay = d * bfhi(sw);
    int e = s;
    for (; e + 12 <= en; e += 12) {
        int2 pp[12]; unsigned gv[12];
        #pragma unroll
        for (int u = 0; u < 12; u++) pp[u] = pairs[e + u];
        #pragma unroll
        for (int u = 0; u < 12; u++) gv[u] = Hu[(size_t)pp[u].x * 32 + li];
        #pragma unroll
        for (int u = 0; u < 12; u++) {
            float nm = __int_as_float(pp[u].y);
            ax = fmaf(nm, bflo(gv[u]), ax);
            ay = fmaf(nm, bfhi(gv[u]), ay);
        }
    }
    for (; e + 4 <= en; e += 4) {
        int2 pp[4]; unsigned gv[4];
        #pragma unroll
        for (int u = 0; u < 4; u++) pp[u] = pairs[e + u];
        #pragma unroll
        for (int u = 0; u < 4; u++) gv[u] = Hu[(size_t)pp[u].x * 32 + li];
        #pragma unroll
        for (int u = 0; u < 4; u++) {
            float nm = __int_as_float(pp[u].y);
            ax = fmaf(nm, bflo(gv[u]), ax);
            ay = fmaf(nm, bfhi(gv[u]), ay);
        }
    }
    for (; e < en; e++) {
        int2 p = pairs[e];
        unsigned g = Hu[(size_t)p.x * 32 + li];
        float nm = __int_as_float(p.y);
        ax = fmaf(nm, bflo(g), ax);
        ay = fmaf(nm, bfhi(g), ay);
    }
    if constexpr (BIAS) {
        float2 bb = reinterpret_cast<const float2*>(bias)[li];
        ax = d * ax + bb.x;
        ay = d * ay + bb.y;
    } else {
        ax = d * ax;
        ay = d * ay;
    }
    Out[(size_t)nd * 32 + li] = f2bf_bits(ax) | (f2bf_bits(ay) << 16);
}

// logits = sigmoid(dot(enc[a], enc[b])) — 8 lanes/pair, bf16 enc (128B rows)
__global__ void k_decode(const unsigned short* __restrict__ enc,
                         const int* __restrict__ eli, int M, float* __restrict__ out)
{
    int gid  = blockIdx.x * 256 + threadIdx.x;
    int pair = gid >> 3;
    int l    = gid & 7;
    if (pair >= M) return;
    int a = eli[pair];
    int b = eli[M + pair];
    const uint4* E4 = (const uint4*)enc;        // 8 uint4 per 64-ch row
    uint4 va = E4[(size_t)a * 8 + l];
    uint4 vb = E4[(size_t)b * 8 + l];
    float s = 0.f;
    s = fmaf(bflo(va.x), bflo(vb.x), s); s = fmaf(bfhi(va.x), bfhi(vb.x), s);
    s = fmaf(bflo(va.y), bflo(vb.y), s); s = fmaf(bfhi(va.y), bfhi(vb.y), s);
    s = fmaf(bflo(va.z), bflo(vb.z), s); s = fmaf(bfhi(va.z), bfhi(vb.z), s);
    s = fmaf(bflo(va.w), bflo(vb.w), s); s = fmaf(bfhi(va.w), bfhi(vb.w), s);
    s += __shfl_xor(s, 4, 8);
    s += __shfl_xor(s, 2, 8);
    s += __shfl_xor(s, 1, 8);
    if (l == 0) out[pair] = 1.f / (1.f + expf(-s));
}

extern "C" void kernel_launch(void* const* d_in, const int* in_sizes, int n_in,
                              void* d_out, int out_size, void* d_ws, size_t ws_size,
                              hipStream_t stream)
{
    const float* x     = (const float*)d_in[0];
    const int*   ei    = (const int*)d_in[1];
    const float* ew    = (const float*)d_in[2];
    const int*   eli   = (const int*)d_in[3];
    const float* W_in  = (const float*)d_in[4];
    const float* b_in  = (const float*)d_in[5];
    const float* W_hid = (const float*)d_in[6];
    const float* b_hid = (const float*)d_in[7];
    const float* W_out = (const float*)d_in[8];
    const float* b_out = (const float*)d_in[9];

    const int n = in_sizes[0] / 64;
    const int E = in_sizes[1] / 2;
    const int M = in_sizes[3] / 2;
    const int* row = ei;
    const int* col = ei + E;

    const int NB   = (n + 255) / 256;
    const int nb_E = (E + 255) / 256;
    const int gb   = (n + 127) / 128;
    const int ab   = (n + 3) / 4;

    // ---- workspace layout (256B-aligned regions) ----
    char* basep = (char*)d_ws;
    size_t off = 0;
    auto alloc = [&](size_t bytes) {
        char* p = basep + off; off = (off + bytes + 255) & ~(size_t)255; return p; };
    float* dinv   = (float*)alloc((size_t)n * 4);
    int*   hist   = (int*)  alloc((size_t)n * 4);
    int*   rowptr = (int*)  alloc((size_t)(n + 1) * 4);
    int*   pos    = (int*)  alloc((size_t)E * 4);
    int*   bsum   = (int*)  alloc(1024 * 4);
    int*   boff   = (int*)  alloc(1024 * 4);
    int2*  pairs  = (int2*) alloc((size_t)E * 8);
    unsigned short* wt_in  = (unsigned short*)alloc((size_t)128 * 64 * 2);
    unsigned short* wt_hid = (unsigned short*)alloc((size_t)4 * 128 * 128 * 2);
    unsigned short* wt_out = (unsigned short*)alloc((size_t)64 * 128 * 2);
    unsigned short* xb     = (unsigned short*)alloc((size_t)n * 64 * 2);   // x bf16
    unsigned short* Hbf    = (unsigned short*)alloc((size_t)n * 128 * 2);  // scratch
    unsigned short* Abf    = (unsigned short*)alloc((size_t)n * 128 * 2);  // activations
    unsigned short* enc    = (unsigned short*)alloc((size_t)n * 64 * 2);   // bf16 enc

    // ---- CSR build (atomics only in k_hist; place is atomic-free) ----
    k_zero<<<NB, 256, 0, stream>>>(hist, n);
    k_hist<<<nb_E, 256, 0, stream>>>(col, hist, pos, E);
    k_scan1<<<NB, 256, 0, stream>>>(hist, rowptr, bsum, n);
    k_scan2<<<1, 256, 0, stream>>>(bsum, boff, NB, rowptr, n);
    k_scan3<<<NB, 256, 0, stream>>>(rowptr, boff, n);
    k_place<<<nb_E, 256, 0, stream>>>(row, col, ew, rowptr, pos, pairs, E);
    k_deg<<<(n * 4 + 255) / 256, 256, 0, stream>>>(pairs, rowptr, dinv, n);
    k_premul<<<nb_E, 256, 0, stream>>>(pairs, dinv, E);

    // ---- prep: x -> bf16 + all weight transposes (single launch) ----
    const long X4 = (long)n * 16;
    k_prep<<<(int)((X4 + 81920 + 255) / 256), 256, 0, stream>>>(
        x, xb, X4, W_in, W_hid, W_out, wt_in, wt_hid, wt_out);

    // ---- layer 1 (aggregate-first): T = A_hat@x ; A1 = relu(T@W_in + b) ----
    k_aggregate64<false><<<(n + 7) / 8, 256, 0, stream>>>(
        xb, pairs, rowptr, dinv, nullptr, (unsigned*)Hbf, n);
    k_gemm_mfma<64, 128, true, true><<<gb, 256, 0, stream>>>(
        Hbf, wt_in, b_in, Abf, n);

    // ---- 4 hidden layers: 128 -> 128 ----
    for (int i = 0; i < 4; i++) {
        k_gemm_mfma<128, 128, true, false><<<gb, 256, 0, stream>>>(
            Abf, wt_hid + (size_t)i * 128 * 128, nullptr, Hbf, n);
        k_aggregate128<true><<<ab, 256, 0, stream>>>(
            Hbf, pairs, rowptr, dinv, b_hid + (size_t)i * 128, (unsigned*)Abf, n);
    }

    // ---- output layer: 128 -> 64 ----
    k_gemm_mfma<128, 64, true, false><<<gb, 256, 0, stream>>>(
        Abf, wt_out, nullptr, Hbf, n);
    k_aggregate64<true><<<(n + 7) / 8, 256, 0, stream>>>(
        Hbf, pairs, rowptr, dinv, b_out, (unsigned*)enc, n);

    // ---- decoder ----
    k_decode<<<(M * 8 + 255) / 256, 256, 0, stream>>>(enc, eli, M, (float*)d_out);
}